// Round 3
// baseline (3044.794 us; speedup 1.0000x reference)
//
#include <hip/hip_runtime.h>
#include <cstdint>
#include <cmath>

#define T_ 2048
#define E_ 4096
#define H_ 16
#define D_ 256
#define NF 32   // rotary freq count (R/2)

__device__ __forceinline__ int dot4(int a, int b, int c) {
#if __has_builtin(__builtin_amdgcn_sdot4)
  return __builtin_amdgcn_sdot4(a, b, c, false);
#else
  c += ((a << 24) >> 24) * ((b << 24) >> 24);
  c += ((a << 16) >> 24) * ((b << 16) >> 24);
  c += ((a <<  8) >> 24) * ((b <<  8) >> 24);
  c += (a >> 24) * (b >> 24);
  return c;
#endif
}

// pack 4 int32 (each holding an int8 value) into one byte-packed int
__device__ __forceinline__ int pack4i(int4 v) {
  return (v.x & 255) | ((v.y & 255) << 8) | ((v.z & 255) << 16) | (v.w << 24);
}

// ---------------- sin/cos table (double-precision, cast to f32) -------------
__global__ void sincos_kernel(float* __restrict__ sinT, float* __restrict__ cosT) {
  int idx = blockIdx.x * 256 + threadIdx.x;   // t*32 + j
  int t = idx >> 5, j = idx & 31;
  float invf = (float)exp(-(double)j * (log(10000.0) / 32.0));
  float ang = (float)t * invf;                // f32 product, matches reference
  sinT[idx] = (float)sin((double)ang);
  cosT[idx] = (float)cos((double)ang);
}

// ---------------- int32 -> int8 repack (16 elements/thread) -----------------
__global__ __launch_bounds__(256) void repack_kernel(const int* __restrict__ src,
                                                     int8_t* __restrict__ dst) {
  size_t i = (size_t)blockIdx.x * 256 + threadIdx.x;   // handles 16 ints
  const int4* s = (const int4*)src + i * 4;
  int4 a = s[0], b = s[1], c = s[2], d = s[3];
  int4 o;
  o.x = pack4i(a); o.y = pack4i(b); o.z = pack4i(c); o.w = pack4i(d);
  ((int4*)dst)[i] = o;
}

// ---------------- QKV projection: int8 GEMM + quant + RoPE ------------------
// grid (T/64, E/64, 3), block 256. mode z: 0=Q,1=K,2=V
template <bool PACKED>
__global__ __launch_bounds__(256) void qkv_gemm(
    const void* __restrict__ xp,
    const void* __restrict__ Wqp, const int* __restrict__ bq,
    const void* __restrict__ Wkp, const int* __restrict__ bk,
    const void* __restrict__ Wvp, const int* __restrict__ bv,
    const float* __restrict__ alpq, const float* __restrict__ betq,
    const float* __restrict__ alpk, const float* __restrict__ betk,
    const float* __restrict__ alpv, const float* __restrict__ betv,
    const float* __restrict__ sinT, const float* __restrict__ cosT,
    int8_t* __restrict__ Q8, int8_t* __restrict__ K8, int8_t* __restrict__ V8)
{
  const int mode = blockIdx.z;
  const void* __restrict__ Wp = (mode == 0) ? Wqp : (mode == 1 ? Wkp : Wvp);
  const int* __restrict__ bs  = (mode == 0) ? bq  : (mode == 1 ? bk  : bv);
  const float alpha = (mode == 0) ? alpq[0] : (mode == 1 ? alpk[0] : alpv[0]);
  const float beta  = (mode == 0) ? betq[0] : (mode == 1 ? betk[0] : betv[0]);

  __shared__ int As[64 * 17];   // [m][k-int], stride 17 breaks bank conflicts
  __shared__ int Bs[64 * 17];   // [n][k-int]

  const int tid = threadIdx.x;
  const int tx = tid & 15, ty = tid >> 4;
  const int t0 = blockIdx.x * 64, o0 = blockIdx.y * 64;
  const int lrow = tid >> 2, lc = tid & 3;

  int acc[4][4] = {};

  for (int e0 = 0; e0 < E_; e0 += 64) {
    int a4[4], b4[4];
    if constexpr (PACKED) {
      const int8_t* xr = (const int8_t*)xp + (size_t)(t0 + lrow) * E_ + e0 + lc * 16;
      const int8_t* wr = (const int8_t*)Wp + (size_t)(o0 + lrow) * E_ + e0 + lc * 16;
      int4 va = *(const int4*)xr;
      int4 vb = *(const int4*)wr;
      a4[0] = va.x; a4[1] = va.y; a4[2] = va.z; a4[3] = va.w;
      b4[0] = vb.x; b4[1] = vb.y; b4[2] = vb.z; b4[3] = vb.w;
    } else {
      const int* xr = (const int*)xp + (size_t)(t0 + lrow) * E_ + e0 + lc * 16;
      const int* wr = (const int*)Wp + (size_t)(o0 + lrow) * E_ + e0 + lc * 16;
      #pragma unroll
      for (int u = 0; u < 4; ++u) a4[u] = pack4i(((const int4*)xr)[u]);
      #pragma unroll
      for (int u = 0; u < 4; ++u) b4[u] = pack4i(((const int4*)wr)[u]);
    }
    __syncthreads();
    int* ap = &As[lrow * 17 + lc * 4];
    ap[0] = a4[0]; ap[1] = a4[1]; ap[2] = a4[2]; ap[3] = a4[3];
    int* bp = &Bs[lrow * 17 + lc * 4];
    bp[0] = b4[0]; bp[1] = b4[1]; bp[2] = b4[2]; bp[3] = b4[3];
    __syncthreads();
    #pragma unroll
    for (int kk = 0; kk < 16; ++kk) {
      int a[4], b[4];
      #pragma unroll
      for (int i = 0; i < 4; ++i) a[i] = As[(ty * 4 + i) * 17 + kk];
      #pragma unroll
      for (int j = 0; j < 4; ++j) b[j] = Bs[(tx * 4 + j) * 17 + kk];
      #pragma unroll
      for (int i = 0; i < 4; ++i)
        #pragma unroll
        for (int j = 0; j < 4; ++j)
          acc[i][j] = dot4(a[i], b[j], acc[i][j]);
    }
  }

  const int ob = o0 + tx * 4;
  const int h  = ob >> 8;
  const int dd = ob & 255;
  int8_t* __restrict__ dst = (mode == 0) ? Q8 : (mode == 1 ? K8 : V8);

  #pragma unroll
  for (int i = 0; i < 4; ++i) {
    const int t = t0 + ty * 4 + i;
    float y[4];
    #pragma unroll
    for (int j = 0; j < 4; ++j) {
      float v = __fadd_rn(__fmul_rn(alpha, (float)acc[i][j]),
                          __fmul_rn(beta, (float)bs[ob + j]));
      v = rintf(v);
      y[j] = fminf(fmaxf(v, -128.0f), 127.0f);
    }
    int q0, q1, q2, q3;
    if (mode < 2 && dd < 64) {
      // RoPE on the int8-quantized values (reference order), then trunc+clip
      const int j0 = dd >> 1;
      const float s0 = sinT[t * NF + j0],     c0 = cosT[t * NF + j0];
      const float s1 = sinT[t * NF + j0 + 1], c1 = cosT[t * NF + j0 + 1];
      float r0 = __fadd_rn(__fmul_rn(y[0], c0), __fmul_rn(-y[1], s0));
      float r1 = __fadd_rn(__fmul_rn(y[1], c0), __fmul_rn( y[0], s0));
      float r2 = __fadd_rn(__fmul_rn(y[2], c1), __fmul_rn(-y[3], s1));
      float r3 = __fadd_rn(__fmul_rn(y[3], c1), __fmul_rn( y[2], s1));
      q0 = (int)fminf(fmaxf(truncf(r0), -128.0f), 127.0f);
      q1 = (int)fminf(fmaxf(truncf(r1), -128.0f), 127.0f);
      q2 = (int)fminf(fmaxf(truncf(r2), -128.0f), 127.0f);
      q3 = (int)fminf(fmaxf(truncf(r3), -128.0f), 127.0f);
    } else {
      q0 = (int)y[0]; q1 = (int)y[1]; q2 = (int)y[2]; q3 = (int)y[3];
    }
    int packed = (q0 & 255) | ((q1 & 255) << 8) | ((q2 & 255) << 16) | ((q3 & 255) << 24);
    *(int*)(dst + ((size_t)h * T_ + t) * D_ + dd) = packed;
  }
}

// ---------------- attention: scores -> softmax -> pi8 -> PV -----------------
// grid (T/16, H), block 256.
__global__ __launch_bounds__(256) void attn_kernel(
    const int8_t* __restrict__ Q8, const int8_t* __restrict__ K8,
    const int8_t* __restrict__ V8,
    const float* __restrict__ p_aqk, const float* __restrict__ p_apv,
    int8_t* __restrict__ attn8)
{
  __shared__ int    qs[16 * 65];
  __shared__ int    Ks[64 * 65];
  __shared__ int8_t pi8[16][2048];
  __shared__ float  mred[16][17], sred[16][17];

  const int h  = blockIdx.y;
  const int t0 = blockIdx.x * 16;
  const int tid = threadIdx.x;
  const float aqk = p_aqk[0] * 0.0625f;   // /16 is exact pow2, commutes
  const float apv = p_apv[0];

  {
    int row = tid >> 4, c = tid & 15;
    int4 v = *(const int4*)(Q8 + ((size_t)h * T_ + t0 + row) * D_ + c * 16);
    int* qp = &qs[row * 65 + c * 4];
    qp[0] = v.x; qp[1] = v.y; qp[2] = v.z; qp[3] = v.w;
  }

  const int row  = tid >> 4;
  const int lane = tid & 15;
  const int tmy  = t0 + row;
  const int send = t0 + 16;
  const int krow = tid >> 2, kc = tid & 3;   // 64 rows x 4 quarter-rows

  // ---- pass 1: online max / sum ----
  float m = -INFINITY, sm = 0.0f;
  for (int s0 = 0; s0 < send; s0 += 64) {
    __syncthreads();
    {
      // full row = 64 ints = 16 int4; each thread loads 4 consecutive int4s
      const int8_t* src = K8 + ((size_t)h * T_ + s0 + krow) * D_ + kc * 64;
      int4 v0 = ((const int4*)src)[0];
      int4 v1 = ((const int4*)src)[1];
      int4 v2 = ((const int4*)src)[2];
      int4 v3 = ((const int4*)src)[3];
      int* kp = &Ks[krow * 65 + kc * 16];
      kp[0]  = v0.x; kp[1]  = v0.y; kp[2]  = v0.z; kp[3]  = v0.w;
      kp[4]  = v1.x; kp[5]  = v1.y; kp[6]  = v1.z; kp[7]  = v1.w;
      kp[8]  = v2.x; kp[9]  = v2.y; kp[10] = v2.z; kp[11] = v2.w;
      kp[12] = v3.x; kp[13] = v3.y; kp[14] = v3.z; kp[15] = v3.w;
    }
    __syncthreads();
    for (int s = s0 + lane; s <= tmy && s < s0 + 64; s += 16) {
      int accs = 0;
      const int* qp = &qs[row * 65];
      const int* kp = &Ks[(s - s0) * 65];
      #pragma unroll
      for (int kk = 0; kk < 64; ++kk) accs = dot4(qp[kk], kp[kk], accs);
      float l = __fmul_rn(aqk, (float)accs);
      if (l > m) { sm = sm * expf(m - l) + 1.0f; m = l; }
      else       { sm += expf(l - m); }
    }
  }
  mred[row][lane] = m; sred[row][lane] = sm;
  __syncthreads();
  float mF = -INFINITY;
  #pragma unroll
  for (int i = 0; i < 16; ++i) mF = fmaxf(mF, mred[row][i]);
  float sF = 0.0f;
  #pragma unroll
  for (int i = 0; i < 16; ++i) sF += sred[row][i] * expf(mred[row][i] - mF);

  // ---- pass 2: recompute scores, quantize probs into LDS ----
  for (int s0 = 0; s0 < send; s0 += 64) {
    __syncthreads();
    {
      const int8_t* src = K8 + ((size_t)h * T_ + s0 + krow) * D_ + kc * 64;
      int4 v0 = ((const int4*)src)[0];
      int4 v1 = ((const int4*)src)[1];
      int4 v2 = ((const int4*)src)[2];
      int4 v3 = ((const int4*)src)[3];
      int* kp = &Ks[krow * 65 + kc * 16];
      kp[0]  = v0.x; kp[1]  = v0.y; kp[2]  = v0.z; kp[3]  = v0.w;
      kp[4]  = v1.x; kp[5]  = v1.y; kp[6]  = v1.z; kp[7]  = v1.w;
      kp[8]  = v2.x; kp[9]  = v2.y; kp[10] = v2.z; kp[11] = v2.w;
      kp[12] = v3.x; kp[13] = v3.y; kp[14] = v3.z; kp[15] = v3.w;
    }
    __syncthreads();
    for (int s = s0 + lane; s < s0 + 64 && s < send; s += 16) {
      float pq = 0.0f;
      if (s <= tmy) {
        int accs = 0;
        const int* qp = &qs[row * 65];
        const int* kp = &Ks[(s - s0) * 65];
        #pragma unroll
        for (int kk = 0; kk < 64; ++kk) accs = dot4(qp[kk], kp[kk], accs);
        float l = __fmul_rn(aqk, (float)accs);
        float p = expf(l - mF) / sF;                 // division first (ref order)
        pq = rintf(__fmul_rn(p, 127.0f));
      }
      pi8[row][s] = (int8_t)(int)pq;
    }
  }
  __syncthreads();

  // ---- PV ----
  const int pk = tid & 63;
  const int r0 = tid >> 6;
  int acc2[4][4] = {};
  const int8_t* vbase = V8 + (size_t)h * T_ * D_ + pk * 4;
  for (int s = 0; s < send; ++s) {
    int vp = *(const int*)(vbase + (size_t)s * D_);
    int b0 = (vp << 24) >> 24;
    int b1 = (vp << 16) >> 24;
    int b2 = (vp <<  8) >> 24;
    int b3 =  vp >> 24;
    #pragma unroll
    for (int k2 = 0; k2 < 4; ++k2) {
      int p = pi8[r0 + k2 * 4][s];
      acc2[k2][0] += p * b0;
      acc2[k2][1] += p * b1;
      acc2[k2][2] += p * b2;
      acc2[k2][3] += p * b3;
    }
  }
  #pragma unroll
  for (int k2 = 0; k2 < 4; ++k2) {
    const int t = t0 + r0 + k2 * 4;
    int q[4];
    #pragma unroll
    for (int j = 0; j < 4; ++j) {
      float y = rintf(__fmul_rn(apv, (float)acc2[k2][j]));
      y = fminf(fmaxf(y, -128.0f), 127.0f);
      q[j] = (int)y;
    }
    int packed = (q[0] & 255) | ((q[1] & 255) << 8) | ((q[2] & 255) << 16) | ((q[3] & 255) << 24);
    *(int*)(attn8 + (size_t)t * E_ + h * D_ + pk * 4) = packed;
  }
}

// ---------------- output projection: int8 GEMM, fp32 epilogue ---------------
template <bool PACKED>
__global__ __launch_bounds__(256) void out_gemm(
    const int8_t* __restrict__ xa, const void* __restrict__ Wop,
    const float* __restrict__ b_out, const float* __restrict__ p_aout,
    float* __restrict__ out)
{
  __shared__ int As[64 * 17];
  __shared__ int Bs[64 * 17];

  const float alpha = p_aout[0];
  const int tid = threadIdx.x;
  const int tx = tid & 15, ty = tid >> 4;
  const int t0 = blockIdx.x * 64, o0 = blockIdx.y * 64;
  const int lrow = tid >> 2, lc = tid & 3;

  int acc[4][4] = {};

  for (int e0 = 0; e0 < E_; e0 += 64) {
    int4 av4 = *(const int4*)(xa + (size_t)(t0 + lrow) * E_ + e0 + lc * 16);
    int b4[4];
    if constexpr (PACKED) {
      int4 vb = *(const int4*)((const int8_t*)Wop + (size_t)(o0 + lrow) * E_ + e0 + lc * 16);
      b4[0] = vb.x; b4[1] = vb.y; b4[2] = vb.z; b4[3] = vb.w;
    } else {
      const int* wr = (const int*)Wop + (size_t)(o0 + lrow) * E_ + e0 + lc * 16;
      #pragma unroll
      for (int u = 0; u < 4; ++u) b4[u] = pack4i(((const int4*)wr)[u]);
    }
    __syncthreads();
    int* ap = &As[lrow * 17 + lc * 4];
    ap[0] = av4.x; ap[1] = av4.y; ap[2] = av4.z; ap[3] = av4.w;
    int* bp = &Bs[lrow * 17 + lc * 4];
    bp[0] = b4[0]; bp[1] = b4[1]; bp[2] = b4[2]; bp[3] = b4[3];
    __syncthreads();
    #pragma unroll
    for (int kk = 0; kk < 16; ++kk) {
      int a[4], b[4];
      #pragma unroll
      for (int i = 0; i < 4; ++i) a[i] = As[(ty * 4 + i) * 17 + kk];
      #pragma unroll
      for (int j = 0; j < 4; ++j) b[j] = Bs[(tx * 4 + j) * 17 + kk];
      #pragma unroll
      for (int i = 0; i < 4; ++i)
        #pragma unroll
        for (int j = 0; j < 4; ++j)
          acc[i][j] = dot4(a[i], b[j], acc[i][j]);
    }
  }

  #pragma unroll
  for (int i = 0; i < 4; ++i) {
    const int t = t0 + ty * 4 + i;
    const int ob = o0 + tx * 4;
    #pragma unroll
    for (int j = 0; j < 4; ++j) {
      out[(size_t)t * E_ + ob + j] =
          __fadd_rn(__fmul_rn(alpha, (float)acc[i][j]), b_out[ob + j]);
    }
  }
}

extern "C" void kernel_launch(void* const* d_in, const int* in_sizes, int n_in,
                              void* d_out, int out_size, void* d_ws, size_t ws_size,
                              hipStream_t stream) {
  // ALL integer inputs arrive as int32 (harness contract: integer -> const int*)
  const int* hs   = (const int*)d_in[0];
  const int* Wq   = (const int*)d_in[1];
  const int* bq   = (const int*)d_in[2];
  const int* Wk   = (const int*)d_in[3];
  const int* bk   = (const int*)d_in[4];
  const int* Wv   = (const int*)d_in[5];
  const int* bv   = (const int*)d_in[6];
  const int* Wo   = (const int*)d_in[7];
  const float* b_out = (const float*)d_in[8];
  const float* aq   = (const float*)d_in[9];
  const float* btq  = (const float*)d_in[10];
  const float* ak   = (const float*)d_in[11];
  const float* btk  = (const float*)d_in[12];
  const float* av   = (const float*)d_in[13];
  const float* btv  = (const float*)d_in[14];
  const float* aqk  = (const float*)d_in[15];
  const float* apv  = (const float*)d_in[16];
  const float* aout = (const float*)d_in[17];

  const size_t SEG = (size_t)H_ * T_ * D_;          // 8 MB
  char* ws = (char*)d_ws;
  int8_t* Q8    = (int8_t*)ws;
  int8_t* K8    = Q8 + SEG;
  int8_t* V8    = K8 + SEG;
  int8_t* attn8 = V8 + SEG;                          // aliased with x8 (safe: x8
  int8_t* x8    = attn8;                             // dead before attn writes)
  float*  sinT  = (float*)(ws + 4 * SEG);
  float*  cosT  = sinT + T_ * NF;
  int8_t* Wq8   = (int8_t*)(cosT + T_ * NF);
  int8_t* Wk8   = Wq8 + (size_t)E_ * E_;
  int8_t* Wv8   = Wk8 + (size_t)E_ * E_;
  int8_t* Wo8   = Wv8 + (size_t)E_ * E_;
  const size_t NEED = 4 * SEG + 2 * (size_t)T_ * NF * 4 + 4 * (size_t)E_ * E_;
  const bool big = (ws_size >= NEED);

  sincos_kernel<<<(T_ * NF) / 256, 256, 0, stream>>>(sinT, cosT);

  if (big) {
    repack_kernel<<<(T_ * E_ / 16) / 256, 256, 0, stream>>>(hs, x8);
    repack_kernel<<<(E_ * E_ / 16) / 256, 256, 0, stream>>>(Wq, Wq8);
    repack_kernel<<<(E_ * E_ / 16) / 256, 256, 0, stream>>>(Wk, Wk8);
    repack_kernel<<<(E_ * E_ / 16) / 256, 256, 0, stream>>>(Wv, Wv8);
    repack_kernel<<<(E_ * E_ / 16) / 256, 256, 0, stream>>>(Wo, Wo8);
    qkv_gemm<true><<<dim3(T_ / 64, E_ / 64, 3), 256, 0, stream>>>(
        x8, Wq8, bq, Wk8, bk, Wv8, bv, aq, btq, ak, btk, av, btv,
        sinT, cosT, Q8, K8, V8);
  } else {
    qkv_gemm<false><<<dim3(T_ / 64, E_ / 64, 3), 256, 0, stream>>>(
        hs, Wq, bq, Wk, bk, Wv, bv, aq, btq, ak, btk, av, btv,
        sinT, cosT, Q8, K8, V8);
  }

  attn_kernel<<<dim3(T_ / 16, H_), 256, 0, stream>>>(Q8, K8, V8, aqk, apv, attn8);

  if (big) {
    out_gemm<true><<<dim3(T_ / 64, E_ / 64), 256, 0, stream>>>(
        attn8, Wo8, b_out, aout, (float*)d_out);
  } else {
    out_gemm<false><<<dim3(T_ / 64, E_ / 64), 256, 0, stream>>>(
        attn8, Wo, b_out, aout, (float*)d_out);
  }
}

// Round 4
// 2328.429 us; speedup vs baseline: 1.3077x; 1.3077x over previous
//
#include <hip/hip_runtime.h>
#include <cstdint>
#include <cmath>

#define T_ 2048
#define E_ 4096
#define H_ 16
#define D_ 256
#define NF 32   // rotary freq count (R/2)

__device__ __forceinline__ int dot4(int a, int b, int c) {
#if __has_builtin(__builtin_amdgcn_sdot4)
  return __builtin_amdgcn_sdot4(a, b, c, false);
#else
  c += ((a << 24) >> 24) * ((b << 24) >> 24);
  c += ((a << 16) >> 24) * ((b << 16) >> 24);
  c += ((a <<  8) >> 24) * ((b <<  8) >> 24);
  c += (a >> 24) * (b >> 24);
  return c;
#endif
}

// pack 4 int32 (each holding an int8 value) into one byte-packed int
__device__ __forceinline__ int pack4i(int4 v) {
  return (v.x & 255) | ((v.y & 255) << 8) | ((v.z & 255) << 16) | (v.w << 24);
}

// ---------------- sin/cos table (double-precision, cast to f32) -------------
__global__ void sincos_kernel(float* __restrict__ sinT, float* __restrict__ cosT) {
  int idx = blockIdx.x * 256 + threadIdx.x;   // t*32 + j
  int t = idx >> 5, j = idx & 31;
  float invf = (float)exp(-(double)j * (log(10000.0) / 32.0));
  float ang = (float)t * invf;                // f32 product, matches reference
  sinT[idx] = (float)sin((double)ang);
  cosT[idx] = (float)cos((double)ang);
}

// ---------------- int32 -> int8 repack (16 elements/thread) -----------------
__global__ __launch_bounds__(256) void repack_kernel(const int* __restrict__ src,
                                                     int8_t* __restrict__ dst) {
  size_t i = (size_t)blockIdx.x * 256 + threadIdx.x;   // handles 16 ints
  const int4* s = (const int4*)src + i * 4;
  int4 a = s[0], b = s[1], c = s[2], d = s[3];
  int4 o;
  o.x = pack4i(a); o.y = pack4i(b); o.z = pack4i(c); o.w = pack4i(d);
  ((int4*)dst)[i] = o;
}

// ---------------- QKV projection: int8 GEMM + quant + RoPE ------------------
// grid (T/64, E/64, 3), block 256. mode z: 0=Q,1=K,2=V
template <bool PACKED>
__global__ __launch_bounds__(256) void qkv_gemm(
    const void* __restrict__ xp,
    const void* __restrict__ Wqp, const int* __restrict__ bq,
    const void* __restrict__ Wkp, const int* __restrict__ bk,
    const void* __restrict__ Wvp, const int* __restrict__ bv,
    const float* __restrict__ alpq, const float* __restrict__ betq,
    const float* __restrict__ alpk, const float* __restrict__ betk,
    const float* __restrict__ alpv, const float* __restrict__ betv,
    const float* __restrict__ sinT, const float* __restrict__ cosT,
    int8_t* __restrict__ Q8, int8_t* __restrict__ K8, int8_t* __restrict__ V8)
{
  const int mode = blockIdx.z;
  const void* __restrict__ Wp = (mode == 0) ? Wqp : (mode == 1 ? Wkp : Wvp);
  const int* __restrict__ bs  = (mode == 0) ? bq  : (mode == 1 ? bk  : bv);
  const float alpha = (mode == 0) ? alpq[0] : (mode == 1 ? alpk[0] : alpv[0]);
  const float beta  = (mode == 0) ? betq[0] : (mode == 1 ? betk[0] : betv[0]);

  __shared__ int As[64 * 17];
  __shared__ int Bs[64 * 17];

  const int tid = threadIdx.x;
  const int tx = tid & 15, ty = tid >> 4;
  const int t0 = blockIdx.x * 64, o0 = blockIdx.y * 64;
  const int lrow = tid >> 2, lc = tid & 3;

  int acc[4][4] = {};

  for (int e0 = 0; e0 < E_; e0 += 64) {
    int a4[4], b4[4];
    if constexpr (PACKED) {
      const int8_t* xr = (const int8_t*)xp + (size_t)(t0 + lrow) * E_ + e0 + lc * 16;
      const int8_t* wr = (const int8_t*)Wp + (size_t)(o0 + lrow) * E_ + e0 + lc * 16;
      int4 va = *(const int4*)xr;
      int4 vb = *(const int4*)wr;
      a4[0] = va.x; a4[1] = va.y; a4[2] = va.z; a4[3] = va.w;
      b4[0] = vb.x; b4[1] = vb.y; b4[2] = vb.z; b4[3] = vb.w;
    } else {
      const int* xr = (const int*)xp + (size_t)(t0 + lrow) * E_ + e0 + lc * 16;
      const int* wr = (const int*)Wp + (size_t)(o0 + lrow) * E_ + e0 + lc * 16;
      #pragma unroll
      for (int u = 0; u < 4; ++u) a4[u] = pack4i(((const int4*)xr)[u]);
      #pragma unroll
      for (int u = 0; u < 4; ++u) b4[u] = pack4i(((const int4*)wr)[u]);
    }
    __syncthreads();
    int* ap = &As[lrow * 17 + lc * 4];
    ap[0] = a4[0]; ap[1] = a4[1]; ap[2] = a4[2]; ap[3] = a4[3];
    int* bp = &Bs[lrow * 17 + lc * 4];
    bp[0] = b4[0]; bp[1] = b4[1]; bp[2] = b4[2]; bp[3] = b4[3];
    __syncthreads();
    #pragma unroll
    for (int kk = 0; kk < 16; ++kk) {
      int a[4], b[4];
      #pragma unroll
      for (int i = 0; i < 4; ++i) a[i] = As[(ty * 4 + i) * 17 + kk];
      #pragma unroll
      for (int j = 0; j < 4; ++j) b[j] = Bs[(tx * 4 + j) * 17 + kk];
      #pragma unroll
      for (int i = 0; i < 4; ++i)
        #pragma unroll
        for (int j = 0; j < 4; ++j)
          acc[i][j] = dot4(a[i], b[j], acc[i][j]);
    }
  }

  const int ob = o0 + tx * 4;
  const int h  = ob >> 8;
  const int dd = ob & 255;
  int8_t* __restrict__ dst = (mode == 0) ? Q8 : (mode == 1 ? K8 : V8);

  #pragma unroll
  for (int i = 0; i < 4; ++i) {
    const int t = t0 + ty * 4 + i;
    float y[4];
    #pragma unroll
    for (int j = 0; j < 4; ++j) {
      float v = __fadd_rn(__fmul_rn(alpha, (float)acc[i][j]),
                          __fmul_rn(beta, (float)bs[ob + j]));
      v = rintf(v);
      y[j] = fminf(fmaxf(v, -128.0f), 127.0f);
    }
    int q0, q1, q2, q3;
    if (mode < 2 && dd < 64) {
      const int j0 = dd >> 1;
      const float s0 = sinT[t * NF + j0],     c0 = cosT[t * NF + j0];
      const float s1 = sinT[t * NF + j0 + 1], c1 = cosT[t * NF + j0 + 1];
      float r0 = __fadd_rn(__fmul_rn(y[0], c0), __fmul_rn(-y[1], s0));
      float r1 = __fadd_rn(__fmul_rn(y[1], c0), __fmul_rn( y[0], s0));
      float r2 = __fadd_rn(__fmul_rn(y[2], c1), __fmul_rn(-y[3], s1));
      float r3 = __fadd_rn(__fmul_rn(y[3], c1), __fmul_rn( y[2], s1));
      q0 = (int)fminf(fmaxf(truncf(r0), -128.0f), 127.0f);
      q1 = (int)fminf(fmaxf(truncf(r1), -128.0f), 127.0f);
      q2 = (int)fminf(fmaxf(truncf(r2), -128.0f), 127.0f);
      q3 = (int)fminf(fmaxf(truncf(r3), -128.0f), 127.0f);
    } else {
      q0 = (int)y[0]; q1 = (int)y[1]; q2 = (int)y[2]; q3 = (int)y[3];
    }
    int packed = (q0 & 255) | ((q1 & 255) << 8) | ((q2 & 255) << 16) | ((q3 & 255) << 24);
    *(int*)(dst + ((size_t)h * T_ + t) * D_ + dd) = packed;
  }
}

// ---------------- attention v2: 64 q-rows/block, 4x4 register tiling --------
// grid (T/64, H), block 256. Pass1: online m/sum. Pass2 fused with PV.
__global__ __launch_bounds__(256) void attn_kernel(
    const int8_t* __restrict__ Q8, const int8_t* __restrict__ K8,
    const int8_t* __restrict__ V8,
    const float* __restrict__ p_aqk, const float* __restrict__ p_apv,
    int8_t* __restrict__ attn8)
{
  __shared__ int Qs[64 * 65];     // 16640 B, loaded once
  __shared__ int KV[16 * 264];    // 16896 B: K tile [64][65] OR Vt [16][264] OR m/s partials
  __shared__ int pi8T[64 * 17];   // 4352 B: packed probs [row][s-chunk]
  // total ~37.9 KB -> 4 blocks/CU

  const int h   = blockIdx.y;
  const int t0  = blockIdx.x * 64;
  const int tid = threadIdx.x;
  const int ty = tid >> 4, tx = tid & 15;
  const float aqk = p_aqk[0] * 0.0625f;   // /16 exact pow2, commutes with rounding
  const float apv = p_apv[0];

  // ---- load Q tile (64 rows x 256 B) ----
  {
    int row = tid >> 2, qc = tid & 3;
    const int8_t* src = Q8 + ((size_t)h * T_ + t0 + row) * D_ + qc * 64;
    int4 v0 = ((const int4*)src)[0];
    int4 v1 = ((const int4*)src)[1];
    int4 v2 = ((const int4*)src)[2];
    int4 v3 = ((const int4*)src)[3];
    int* qp = &Qs[row * 65 + qc * 16];
    qp[0]  = v0.x; qp[1]  = v0.y; qp[2]  = v0.z; qp[3]  = v0.w;
    qp[4]  = v1.x; qp[5]  = v1.y; qp[6]  = v1.z; qp[7]  = v1.w;
    qp[8]  = v2.x; qp[9]  = v2.y; qp[10] = v2.z; qp[11] = v2.w;
    qp[12] = v3.x; qp[13] = v3.y; qp[14] = v3.z; qp[15] = v3.w;
  }

  // ---- pass 1: online max / sum, 4 rows x 4 s per thread ----
  float m[4], sm[4];
  #pragma unroll
  for (int i = 0; i < 4; ++i) { m[i] = -INFINITY; sm[i] = 0.0f; }

  for (int s0 = 0; s0 <= t0; s0 += 64) {
    __syncthreads();
    {
      int row = tid >> 2, kc = tid & 3;
      const int8_t* src = K8 + ((size_t)h * T_ + s0 + row) * D_ + kc * 64;
      int4 v0 = ((const int4*)src)[0];
      int4 v1 = ((const int4*)src)[1];
      int4 v2 = ((const int4*)src)[2];
      int4 v3 = ((const int4*)src)[3];
      int* kp = &KV[row * 65 + kc * 16];
      kp[0]  = v0.x; kp[1]  = v0.y; kp[2]  = v0.z; kp[3]  = v0.w;
      kp[4]  = v1.x; kp[5]  = v1.y; kp[6]  = v1.z; kp[7]  = v1.w;
      kp[8]  = v2.x; kp[9]  = v2.y; kp[10] = v2.z; kp[11] = v2.w;
      kp[12] = v3.x; kp[13] = v3.y; kp[14] = v3.z; kp[15] = v3.w;
    }
    __syncthreads();
    int acc[4][4] = {};
    #pragma unroll 8
    for (int kk = 0; kk < 64; ++kk) {
      int a[4], b[4];
      #pragma unroll
      for (int i = 0; i < 4; ++i) a[i] = Qs[(ty * 4 + i) * 65 + kk];
      #pragma unroll
      for (int j = 0; j < 4; ++j) b[j] = KV[(tx * 4 + j) * 65 + kk];
      #pragma unroll
      for (int i = 0; i < 4; ++i)
        #pragma unroll
        for (int j = 0; j < 4; ++j)
          acc[i][j] = dot4(a[i], b[j], acc[i][j]);
    }
    const bool diag = (s0 == t0);
    #pragma unroll
    for (int i = 0; i < 4; ++i) {
      const int trow = t0 + ty * 4 + i;
      #pragma unroll
      for (int j = 0; j < 4; ++j) {
        const int s = s0 + tx * 4 + j;
        if (!diag || s <= trow) {
          float l = __fmul_rn(aqk, (float)acc[i][j]);
          if (l > m[i]) { sm[i] = sm[i] * expf(m[i] - l) + 1.0f; m[i] = l; }
          else          { sm[i] += expf(l - m[i]); }
        }
      }
    }
  }

  // ---- reduce (m, sm) across the 16 tx threads per row (overlay on KV) ----
  float* mred = (float*)KV;          // [64][17]
  float* sred = mred + 64 * 17;      // [64][17]  (2176 floats <= 4224 ints)
  __syncthreads();
  #pragma unroll
  for (int i = 0; i < 4; ++i) {
    mred[(ty * 4 + i) * 17 + tx] = m[i];
    sred[(ty * 4 + i) * 17 + tx] = sm[i];
  }
  __syncthreads();
  float mF[4], sF[4];
  #pragma unroll
  for (int i = 0; i < 4; ++i) {
    const int r = ty * 4 + i;
    float mm = -INFINITY;
    #pragma unroll
    for (int u = 0; u < 16; ++u) mm = fmaxf(mm, mred[r * 17 + u]);
    float ss = 0.0f;
    #pragma unroll
    for (int u = 0; u < 16; ++u) ss += sred[r * 17 + u] * expf(mred[r * 17 + u] - mm);
    mF[i] = mm; sF[i] = ss;
  }

  // ---- pass 2 fused with PV ----
  const int d0 = tid & 63;    // int-pack of d: bytes 4*d0 .. 4*d0+3
  const int r0 = tid >> 6;    // rows r0 + 4k
  int pv[16][4] = {};

  for (int s0 = 0; s0 <= t0; s0 += 64) {
    __syncthreads();   // prev PV / reduction reads done
    {
      int row = tid >> 2, kc = tid & 3;
      const int8_t* src = K8 + ((size_t)h * T_ + s0 + row) * D_ + kc * 64;
      int4 v0 = ((const int4*)src)[0];
      int4 v1 = ((const int4*)src)[1];
      int4 v2 = ((const int4*)src)[2];
      int4 v3 = ((const int4*)src)[3];
      int* kp = &KV[row * 65 + kc * 16];
      kp[0]  = v0.x; kp[1]  = v0.y; kp[2]  = v0.z; kp[3]  = v0.w;
      kp[4]  = v1.x; kp[5]  = v1.y; kp[6]  = v1.z; kp[7]  = v1.w;
      kp[8]  = v2.x; kp[9]  = v2.y; kp[10] = v2.z; kp[11] = v2.w;
      kp[12] = v3.x; kp[13] = v3.y; kp[14] = v3.z; kp[15] = v3.w;
    }
    __syncthreads();
    int acc[4][4] = {};
    #pragma unroll 8
    for (int kk = 0; kk < 64; ++kk) {
      int a[4], b[4];
      #pragma unroll
      for (int i = 0; i < 4; ++i) a[i] = Qs[(ty * 4 + i) * 65 + kk];
      #pragma unroll
      for (int j = 0; j < 4; ++j) b[j] = KV[(tx * 4 + j) * 65 + kk];
      #pragma unroll
      for (int i = 0; i < 4; ++i)
        #pragma unroll
        for (int j = 0; j < 4; ++j)
          acc[i][j] = dot4(a[i], b[j], acc[i][j]);
    }
    const bool diag = (s0 == t0);
    #pragma unroll
    for (int i = 0; i < 4; ++i) {
      const int trow = t0 + ty * 4 + i;
      int pk = 0;
      #pragma unroll
      for (int j = 0; j < 4; ++j) {
        const int s = s0 + tx * 4 + j;
        int q = 0;
        if (!diag || s <= trow) {
          float l = __fmul_rn(aqk, (float)acc[i][j]);
          float p = expf(l - mF[i]) / sF[i];            // division first (ref order)
          q = (int)rintf(__fmul_rn(p, 127.0f));
        }
        pk |= (q & 255) << (8 * j);
      }
      pi8T[(ty * 4 + i) * 17 + tx] = pk;
    }
    __syncthreads();   // scores done with KV; pi8T complete
    // ---- V tile, byte-transposed: KV as Vt[16][264]; Vt[sc][d] = bytes V[s0+4sc+{0..3}][d]
    {
      int sc = tid >> 4, dq = tid & 15;
      const int8_t* vsrc = V8 + ((size_t)h * T_ + s0 + 4 * sc) * D_ + dq * 16;
      int4 rv0 = ((const int4*)(vsrc + 0 * D_))[0];
      int4 rv1 = ((const int4*)(vsrc + 1 * D_))[0];
      int4 rv2 = ((const int4*)(vsrc + 2 * D_))[0];
      int4 rv3 = ((const int4*)(vsrc + 3 * D_))[0];
      int rr0[4] = {rv0.x, rv0.y, rv0.z, rv0.w};
      int rr1[4] = {rv1.x, rv1.y, rv1.z, rv1.w};
      int rr2[4] = {rv2.x, rv2.y, rv2.z, rv2.w};
      int rr3[4] = {rv3.x, rv3.y, rv3.z, rv3.w};
      int* vt = &KV[sc * 264 + dq * 16];
      #pragma unroll
      for (int u = 0; u < 4; ++u) {
        #pragma unroll
        for (int b = 0; b < 4; ++b) {
          int sh = 8 * b;
          vt[u * 4 + b] = ((rr0[u] >> sh) & 255) |
                          (((rr1[u] >> sh) & 255) << 8) |
                          (((rr2[u] >> sh) & 255) << 16) |
                          (((rr3[u] >> sh) & 255) << 24);
        }
      }
    }
    __syncthreads();
    // ---- PV accumulate (masked entries have pi8 == 0, so full tile is safe)
    #pragma unroll
    for (int sc = 0; sc < 16; ++sc) {
      int4 vv = *(const int4*)&KV[sc * 264 + d0 * 4];
      #pragma unroll
      for (int k = 0; k < 16; ++k) {
        int p = pi8T[(r0 + 4 * k) * 17 + sc];
        pv[k][0] = dot4(p, vv.x, pv[k][0]);
        pv[k][1] = dot4(p, vv.y, pv[k][1]);
        pv[k][2] = dot4(p, vv.z, pv[k][2]);
        pv[k][3] = dot4(p, vv.w, pv[k][3]);
      }
    }
  }

  // ---- epilogue: quantize PV, write attn8[t][h*256 + d] ----
  #pragma unroll
  for (int k = 0; k < 16; ++k) {
    const int t = t0 + r0 + 4 * k;
    int q[4];
    #pragma unroll
    for (int b = 0; b < 4; ++b) {
      float y = rintf(__fmul_rn(apv, (float)pv[k][b]));
      y = fminf(fmaxf(y, -128.0f), 127.0f);
      q[b] = (int)y;
    }
    int packed = (q[0] & 255) | ((q[1] & 255) << 8) | ((q[2] & 255) << 16) | ((q[3] & 255) << 24);
    *(int*)(attn8 + (size_t)t * E_ + h * D_ + d0 * 4) = packed;
  }
}

// ---------------- output projection: int8 GEMM, fp32 epilogue ---------------
template <bool PACKED>
__global__ __launch_bounds__(256) void out_gemm(
    const int8_t* __restrict__ xa, const void* __restrict__ Wop,
    const float* __restrict__ b_out, const float* __restrict__ p_aout,
    float* __restrict__ out)
{
  __shared__ int As[64 * 17];
  __shared__ int Bs[64 * 17];

  const float alpha = p_aout[0];
  const int tid = threadIdx.x;
  const int tx = tid & 15, ty = tid >> 4;
  const int t0 = blockIdx.x * 64, o0 = blockIdx.y * 64;
  const int lrow = tid >> 2, lc = tid & 3;

  int acc[4][4] = {};

  for (int e0 = 0; e0 < E_; e0 += 64) {
    int4 av4 = *(const int4*)(xa + (size_t)(t0 + lrow) * E_ + e0 + lc * 16);
    int b4[4];
    if constexpr (PACKED) {
      int4 vb = *(const int4*)((const int8_t*)Wop + (size_t)(o0 + lrow) * E_ + e0 + lc * 16);
      b4[0] = vb.x; b4[1] = vb.y; b4[2] = vb.z; b4[3] = vb.w;
    } else {
      const int* wr = (const int*)Wop + (size_t)(o0 + lrow) * E_ + e0 + lc * 16;
      #pragma unroll
      for (int u = 0; u < 4; ++u) b4[u] = pack4i(((const int4*)wr)[u]);
    }
    __syncthreads();
    int* ap = &As[lrow * 17 + lc * 4];
    ap[0] = av4.x; ap[1] = av4.y; ap[2] = av4.z; ap[3] = av4.w;
    int* bp = &Bs[lrow * 17 + lc * 4];
    bp[0] = b4[0]; bp[1] = b4[1]; bp[2] = b4[2]; bp[3] = b4[3];
    __syncthreads();
    #pragma unroll
    for (int kk = 0; kk < 16; ++kk) {
      int a[4], b[4];
      #pragma unroll
      for (int i = 0; i < 4; ++i) a[i] = As[(ty * 4 + i) * 17 + kk];
      #pragma unroll
      for (int j = 0; j < 4; ++j) b[j] = Bs[(tx * 4 + j) * 17 + kk];
      #pragma unroll
      for (int i = 0; i < 4; ++i)
        #pragma unroll
        for (int j = 0; j < 4; ++j)
          acc[i][j] = dot4(a[i], b[j], acc[i][j]);
    }
  }

  #pragma unroll
  for (int i = 0; i < 4; ++i) {
    const int t = t0 + ty * 4 + i;
    const int ob = o0 + tx * 4;
    #pragma unroll
    for (int j = 0; j < 4; ++j) {
      out[(size_t)t * E_ + ob + j] =
          __fadd_rn(__fmul_rn(alpha, (float)acc[i][j]), b_out[ob + j]);
    }
  }
}

extern "C" void kernel_launch(void* const* d_in, const int* in_sizes, int n_in,
                              void* d_out, int out_size, void* d_ws, size_t ws_size,
                              hipStream_t stream) {
  const int* hs   = (const int*)d_in[0];
  const int* Wq   = (const int*)d_in[1];
  const int* bq   = (const int*)d_in[2];
  const int* Wk   = (const int*)d_in[3];
  const int* bk   = (const int*)d_in[4];
  const int* Wv   = (const int*)d_in[5];
  const int* bv   = (const int*)d_in[6];
  const int* Wo   = (const int*)d_in[7];
  const float* b_out = (const float*)d_in[8];
  const float* aq   = (const float*)d_in[9];
  const float* btq  = (const float*)d_in[10];
  const float* ak   = (const float*)d_in[11];
  const float* btk  = (const float*)d_in[12];
  const float* av   = (const float*)d_in[13];
  const float* btv  = (const float*)d_in[14];
  const float* aqk  = (const float*)d_in[15];
  const float* apv  = (const float*)d_in[16];
  const float* aout = (const float*)d_in[17];

  const size_t SEG = (size_t)H_ * T_ * D_;          // 8 MB
  char* ws = (char*)d_ws;
  int8_t* Q8    = (int8_t*)ws;
  int8_t* K8    = Q8 + SEG;
  int8_t* V8    = K8 + SEG;
  int8_t* attn8 = V8 + SEG;                          // aliased with x8 (safe: x8
  int8_t* x8    = attn8;                             // dead before attn writes)
  float*  sinT  = (float*)(ws + 4 * SEG);
  float*  cosT  = sinT + T_ * NF;
  int8_t* Wq8   = (int8_t*)(cosT + T_ * NF);
  int8_t* Wk8   = Wq8 + (size_t)E_ * E_;
  int8_t* Wv8   = Wk8 + (size_t)E_ * E_;
  int8_t* Wo8   = Wv8 + (size_t)E_ * E_;
  const size_t NEED = 4 * SEG + 2 * (size_t)T_ * NF * 4 + 4 * (size_t)E_ * E_;
  const bool big = (ws_size >= NEED);

  sincos_kernel<<<(T_ * NF) / 256, 256, 0, stream>>>(sinT, cosT);

  if (big) {
    repack_kernel<<<(T_ * E_ / 16) / 256, 256, 0, stream>>>(hs, x8);
    repack_kernel<<<(E_ * E_ / 16) / 256, 256, 0, stream>>>(Wq, Wq8);
    repack_kernel<<<(E_ * E_ / 16) / 256, 256, 0, stream>>>(Wk, Wk8);
    repack_kernel<<<(E_ * E_ / 16) / 256, 256, 0, stream>>>(Wv, Wv8);
    repack_kernel<<<(E_ * E_ / 16) / 256, 256, 0, stream>>>(Wo, Wo8);
    qkv_gemm<true><<<dim3(T_ / 64, E_ / 64, 3), 256, 0, stream>>>(
        x8, Wq8, bq, Wk8, bk, Wv8, bv, aq, btq, ak, btk, av, btv,
        sinT, cosT, Q8, K8, V8);
  } else {
    qkv_gemm<false><<<dim3(T_ / 64, E_ / 64, 3), 256, 0, stream>>>(
        hs, Wq, bq, Wk, bk, Wv, bv, aq, btq, ak, btk, av, btv,
        sinT, cosT, Q8, K8, V8);
  }

  attn_kernel<<<dim3(T_ / 64, H_), 256, 0, stream>>>(Q8, K8, V8, aqk, apv, attn8);

  if (big) {
    out_gemm<true><<<dim3(T_ / 64, E_ / 64), 256, 0, stream>>>(
        attn8, Wo8, b_out, aout, (float*)d_out);
  } else {
    out_gemm<false><<<dim3(T_ / 64, E_ / 64), 256, 0, stream>>>(
        attn8, Wo, b_out, aout, (float*)d_out);
  }
}

// Round 5
// 1142.694 us; speedup vs baseline: 2.6646x; 2.0377x over previous
//
#include <hip/hip_runtime.h>
#include <cstdint>
#include <cmath>

#define T_ 2048
#define E_ 4096
#define H_ 16
#define D_ 256
#define NF 32   // rotary freq count (R/2)

typedef int v4i  __attribute__((ext_vector_type(4)));

__device__ __forceinline__ int dot4(int a, int b, int c) {
#if __has_builtin(__builtin_amdgcn_sdot4)
  return __builtin_amdgcn_sdot4(a, b, c, false);
#else
  c += ((a << 24) >> 24) * ((b << 24) >> 24);
  c += ((a << 16) >> 24) * ((b << 16) >> 24);
  c += ((a <<  8) >> 24) * ((b <<  8) >> 24);
  c += (a >> 24) * (b >> 24);
  return c;
#endif
}

__device__ __forceinline__ int pack4i(int4 v) {
  return (v.x & 255) | ((v.y & 255) << 8) | ((v.z & 255) << 16) | (v.w << 24);
}

#define GLD_LDS16(g, l)                                                        \
  __builtin_amdgcn_global_load_lds(                                            \
      (const __attribute__((address_space(1))) void*)(g),                      \
      (__attribute__((address_space(3))) void*)(l), 16, 0, 0)

// ---------------- sin/cos table (double-precision, cast to f32) -------------
__global__ void sincos_kernel(float* __restrict__ sinT, float* __restrict__ cosT) {
  int idx = blockIdx.x * 256 + threadIdx.x;   // t*32 + j
  int t = idx >> 5, j = idx & 31;
  float invf = (float)exp(-(double)j * (log(10000.0) / 32.0));
  float ang = (float)t * invf;                // f32 product, matches reference
  sinT[idx] = (float)sin((double)ang);
  cosT[idx] = (float)cos((double)ang);
}

// ---------------- int32 -> int8 repack (16 elements/thread) -----------------
__global__ __launch_bounds__(256) void repack_kernel(const int* __restrict__ src,
                                                     int8_t* __restrict__ dst) {
  size_t i = (size_t)blockIdx.x * 256 + threadIdx.x;
  const int4* s = (const int4*)src + i * 4;
  int4 a = s[0], b = s[1], c = s[2], d = s[3];
  int4 o;
  o.x = pack4i(a); o.y = pack4i(b); o.z = pack4i(c); o.w = pack4i(d);
  ((int4*)dst)[i] = o;
}

// =================== MFMA int8 GEMM: QKV projection =========================
// grid (T/128, E/128, 3), block 256 (4 waves, each a 64x64 quadrant).
// C = x8(M,K) * W8^T(N,K); epilogue: quantize (pre-RoPE) -> Q8/K8/V8[h][t][d].
__global__ __launch_bounds__(256) void qkv_gemm_mfma(
    const int8_t* __restrict__ x8,
    const int8_t* __restrict__ Wq8, const int* __restrict__ bq,
    const int8_t* __restrict__ Wk8, const int* __restrict__ bk,
    const int8_t* __restrict__ Wv8, const int* __restrict__ bv,
    const float* __restrict__ alpq, const float* __restrict__ betq,
    const float* __restrict__ alpk, const float* __restrict__ betk,
    const float* __restrict__ alpv, const float* __restrict__ betv,
    int8_t* __restrict__ Q8, int8_t* __restrict__ K8, int8_t* __restrict__ V8)
{
  const int mode = blockIdx.z;
  const int8_t* __restrict__ W = (mode == 0) ? Wq8 : (mode == 1 ? Wk8 : Wv8);
  const int* __restrict__ bs   = (mode == 0) ? bq  : (mode == 1 ? bk  : bv);
  const float alpha = (mode == 0) ? alpq[0] : (mode == 1 ? alpk[0] : alpv[0]);
  const float beta  = (mode == 0) ? betq[0] : (mode == 1 ? betk[0] : betv[0]);

  __shared__ int8_t As[128 * 64];   // row stride 64 B (lane-order for global_load_lds)
  __shared__ int8_t Bs[128 * 64];

  const int tid  = threadIdx.x;
  const int wave = tid >> 6, lane = tid & 63;
  const int wm = wave >> 1, wn = wave & 1;
  const int t0 = blockIdx.x * 128, o0 = blockIdx.y * 128;

  const int srow = lane >> 2;          // 0..15 row within 16-row group
  const int scol = (lane & 3) * 16;    // 0/16/32/48 byte within 64B K-slab
  const int col  = lane & 15;
  const int quad = lane >> 4;

  v4i acc[4][4] = {};

  const int8_t* gA0 = x8 + (size_t)(t0 + wave * 32 + srow) * E_ + scol;
  const int8_t* gB0 = W  + (size_t)(o0 + wave * 32 + srow) * E_ + scol;

  for (int e0 = 0; e0 < E_; e0 += 64) {
    __syncthreads();                    // previous compute done before overwrite
    GLD_LDS16(gA0 + e0,                 As + wave * 2048);
    GLD_LDS16(gA0 + e0 + 16 * E_,       As + wave * 2048 + 1024);
    GLD_LDS16(gB0 + e0,                 Bs + wave * 2048);
    GLD_LDS16(gB0 + e0 + 16 * E_,       Bs + wave * 2048 + 1024);
    __syncthreads();                    // drain vmcnt into LDS

    v4i a[4], b[4];
    #pragma unroll
    for (int i = 0; i < 4; ++i)
      a[i] = *(const v4i*)(As + (wm * 64 + i * 16 + col) * 64 + quad * 16);
    #pragma unroll
    for (int j = 0; j < 4; ++j)
      b[j] = *(const v4i*)(Bs + (wn * 64 + j * 16 + col) * 64 + quad * 16);
    #pragma unroll
    for (int i = 0; i < 4; ++i)
      #pragma unroll
      for (int j = 0; j < 4; ++j)
        acc[i][j] = __builtin_amdgcn_mfma_i32_16x16x64_i8(a[i], b[j], acc[i][j], 0, 0, 0);
  }

  int8_t* __restrict__ dst = (mode == 0) ? Q8 : (mode == 1 ? K8 : V8);
  #pragma unroll
  for (int j = 0; j < 4; ++j) {
    const int o  = o0 + wn * 64 + j * 16 + col;
    const int h  = o >> 8;
    const int dd = o & 255;
    const float bb = (float)bs[o];
    #pragma unroll
    for (int i = 0; i < 4; ++i) {
      #pragma unroll
      for (int r = 0; r < 4; ++r) {
        const int t = t0 + wm * 64 + i * 16 + quad * 4 + r;
        float v = __fadd_rn(__fmul_rn(alpha, (float)acc[i][j][r]),
                            __fmul_rn(beta, bb));
        v = rintf(v);
        v = fminf(fmaxf(v, -128.0f), 127.0f);
        dst[((size_t)h * T_ + t) * D_ + dd] = (int8_t)(int)v;
      }
    }
  }
}

// =================== RoPE pass (in-place on Q8/K8, d<64) ====================
// grid: 2*H*T*4/256. Pairs are adjacent bytes within each packed int.
__global__ __launch_bounds__(256) void rope_kernel(
    int8_t* __restrict__ Q8, int8_t* __restrict__ K8,
    const float* __restrict__ sinT, const float* __restrict__ cosT)
{
  int idx = blockIdx.x * 256 + threadIdx.x;
  int c = idx & 3;
  int t = (idx >> 2) & (T_ - 1);
  int h = (idx >> 13) & (H_ - 1);
  int m = idx >> 17;
  int8_t* base = (m == 0 ? Q8 : K8) + ((size_t)h * T_ + t) * D_ + c * 16;
  int4 v = *(int4*)base;
  int u[4] = {v.x, v.y, v.z, v.w};
  const int jb = c * 8;
  #pragma unroll
  for (int ui = 0; ui < 4; ++ui) {
    const int j = jb + ui * 2;
    const float s0 = sinT[t * NF + j],     c0 = cosT[t * NF + j];
    const float s1 = sinT[t * NF + j + 1], c1 = cosT[t * NF + j + 1];
    const int w = u[ui];
    float y0 = (float)((w << 24) >> 24);
    float y1 = (float)((w << 16) >> 24);
    float y2 = (float)((w <<  8) >> 24);
    float y3 = (float)(w >> 24);
    float r0 = __fadd_rn(__fmul_rn(y0, c0), __fmul_rn(-y1, s0));
    float r1 = __fadd_rn(__fmul_rn(y1, c0), __fmul_rn( y0, s0));
    float r2 = __fadd_rn(__fmul_rn(y2, c1), __fmul_rn(-y3, s1));
    float r3 = __fadd_rn(__fmul_rn(y3, c1), __fmul_rn( y2, s1));
    int q0 = (int)fminf(fmaxf(truncf(r0), -128.0f), 127.0f);
    int q1 = (int)fminf(fmaxf(truncf(r1), -128.0f), 127.0f);
    int q2 = (int)fminf(fmaxf(truncf(r2), -128.0f), 127.0f);
    int q3 = (int)fminf(fmaxf(truncf(r3), -128.0f), 127.0f);
    u[ui] = (q0 & 255) | ((q1 & 255) << 8) | ((q2 & 255) << 16) | ((q3 & 255) << 24);
  }
  int4 ov; ov.x = u[0]; ov.y = u[1]; ov.z = u[2]; ov.w = u[3];
  *(int4*)base = ov;
}

// =================== MFMA int8 GEMM: output projection =======================
// grid (T/128, E/128), block 256. out = alpha*attn8*Wo8^T + b_out (fp32).
__global__ __launch_bounds__(256) void out_gemm_mfma(
    const int8_t* __restrict__ xa, const int8_t* __restrict__ Wo8,
    const float* __restrict__ b_out, const float* __restrict__ p_aout,
    float* __restrict__ out)
{
  const float alpha = p_aout[0];
  __shared__ int8_t As[128 * 64];
  __shared__ int8_t Bs[128 * 64];

  const int tid  = threadIdx.x;
  const int wave = tid >> 6, lane = tid & 63;
  const int wm = wave >> 1, wn = wave & 1;
  const int t0 = blockIdx.x * 128, o0 = blockIdx.y * 128;
  const int srow = lane >> 2, scol = (lane & 3) * 16;
  const int col = lane & 15, quad = lane >> 4;

  v4i acc[4][4] = {};
  const int8_t* gA0 = xa  + (size_t)(t0 + wave * 32 + srow) * E_ + scol;
  const int8_t* gB0 = Wo8 + (size_t)(o0 + wave * 32 + srow) * E_ + scol;

  for (int e0 = 0; e0 < E_; e0 += 64) {
    __syncthreads();
    GLD_LDS16(gA0 + e0,            As + wave * 2048);
    GLD_LDS16(gA0 + e0 + 16 * E_,  As + wave * 2048 + 1024);
    GLD_LDS16(gB0 + e0,            Bs + wave * 2048);
    GLD_LDS16(gB0 + e0 + 16 * E_,  Bs + wave * 2048 + 1024);
    __syncthreads();

    v4i a[4], b[4];
    #pragma unroll
    for (int i = 0; i < 4; ++i)
      a[i] = *(const v4i*)(As + (wm * 64 + i * 16 + col) * 64 + quad * 16);
    #pragma unroll
    for (int j = 0; j < 4; ++j)
      b[j] = *(const v4i*)(Bs + (wn * 64 + j * 16 + col) * 64 + quad * 16);
    #pragma unroll
    for (int i = 0; i < 4; ++i)
      #pragma unroll
      for (int j = 0; j < 4; ++j)
        acc[i][j] = __builtin_amdgcn_mfma_i32_16x16x64_i8(a[i], b[j], acc[i][j], 0, 0, 0);
  }

  #pragma unroll
  for (int j = 0; j < 4; ++j) {
    const int o = o0 + wn * 64 + j * 16 + col;
    const float bb = b_out[o];
    #pragma unroll
    for (int i = 0; i < 4; ++i) {
      #pragma unroll
      for (int r = 0; r < 4; ++r) {
        const int t = t0 + wm * 64 + i * 16 + quad * 4 + r;
        out[(size_t)t * E_ + o] = __fadd_rn(__fmul_rn(alpha, (float)acc[i][j][r]), bb);
      }
    }
  }
}

// ---------------- attention: 64 q-rows/block, 4x4 register tiling -----------
__global__ __launch_bounds__(256) void attn_kernel(
    const int8_t* __restrict__ Q8, const int8_t* __restrict__ K8,
    const int8_t* __restrict__ V8,
    const float* __restrict__ p_aqk, const float* __restrict__ p_apv,
    int8_t* __restrict__ attn8)
{
  __shared__ int Qs[64 * 65];
  __shared__ int KV[16 * 264];
  __shared__ int pi8T[64 * 17];

  const int h   = blockIdx.y;
  const int t0  = blockIdx.x * 64;
  const int tid = threadIdx.x;
  const int ty = tid >> 4, tx = tid & 15;
  const float aqk = p_aqk[0] * 0.0625f;
  const float apv = p_apv[0];

  {
    int row = tid >> 2, qc = tid & 3;
    const int8_t* src = Q8 + ((size_t)h * T_ + t0 + row) * D_ + qc * 64;
    int4 v0 = ((const int4*)src)[0];
    int4 v1 = ((const int4*)src)[1];
    int4 v2 = ((const int4*)src)[2];
    int4 v3 = ((const int4*)src)[3];
    int* qp = &Qs[row * 65 + qc * 16];
    qp[0]  = v0.x; qp[1]  = v0.y; qp[2]  = v0.z; qp[3]  = v0.w;
    qp[4]  = v1.x; qp[5]  = v1.y; qp[6]  = v1.z; qp[7]  = v1.w;
    qp[8]  = v2.x; qp[9]  = v2.y; qp[10] = v2.z; qp[11] = v2.w;
    qp[12] = v3.x; qp[13] = v3.y; qp[14] = v3.z; qp[15] = v3.w;
  }

  float m[4], sm[4];
  #pragma unroll
  for (int i = 0; i < 4; ++i) { m[i] = -INFINITY; sm[i] = 0.0f; }

  for (int s0 = 0; s0 <= t0; s0 += 64) {
    __syncthreads();
    {
      int row = tid >> 2, kc = tid & 3;
      const int8_t* src = K8 + ((size_t)h * T_ + s0 + row) * D_ + kc * 64;
      int4 v0 = ((const int4*)src)[0];
      int4 v1 = ((const int4*)src)[1];
      int4 v2 = ((const int4*)src)[2];
      int4 v3 = ((const int4*)src)[3];
      int* kp = &KV[row * 65 + kc * 16];
      kp[0]  = v0.x; kp[1]  = v0.y; kp[2]  = v0.z; kp[3]  = v0.w;
      kp[4]  = v1.x; kp[5]  = v1.y; kp[6]  = v1.z; kp[7]  = v1.w;
      kp[8]  = v2.x; kp[9]  = v2.y; kp[10] = v2.z; kp[11] = v2.w;
      kp[12] = v3.x; kp[13] = v3.y; kp[14] = v3.z; kp[15] = v3.w;
    }
    __syncthreads();
    int acc[4][4] = {};
    #pragma unroll 8
    for (int kk = 0; kk < 64; ++kk) {
      int a[4], b[4];
      #pragma unroll
      for (int i = 0; i < 4; ++i) a[i] = Qs[(ty * 4 + i) * 65 + kk];
      #pragma unroll
      for (int j = 0; j < 4; ++j) b[j] = KV[(tx * 4 + j) * 65 + kk];
      #pragma unroll
      for (int i = 0; i < 4; ++i)
        #pragma unroll
        for (int j = 0; j < 4; ++j)
          acc[i][j] = dot4(a[i], b[j], acc[i][j]);
    }
    const bool diag = (s0 == t0);
    #pragma unroll
    for (int i = 0; i < 4; ++i) {
      const int trow = t0 + ty * 4 + i;
      #pragma unroll
      for (int j = 0; j < 4; ++j) {
        const int s = s0 + tx * 4 + j;
        if (!diag || s <= trow) {
          float l = __fmul_rn(aqk, (float)acc[i][j]);
          if (l > m[i]) { sm[i] = sm[i] * expf(m[i] - l) + 1.0f; m[i] = l; }
          else          { sm[i] += expf(l - m[i]); }
        }
      }
    }
  }

  float* mred = (float*)KV;
  float* sred = mred + 64 * 17;
  __syncthreads();
  #pragma unroll
  for (int i = 0; i < 4; ++i) {
    mred[(ty * 4 + i) * 17 + tx] = m[i];
    sred[(ty * 4 + i) * 17 + tx] = sm[i];
  }
  __syncthreads();
  float mF[4], sF[4];
  #pragma unroll
  for (int i = 0; i < 4; ++i) {
    const int r = ty * 4 + i;
    float mm = -INFINITY;
    #pragma unroll
    for (int u = 0; u < 16; ++u) mm = fmaxf(mm, mred[r * 17 + u]);
    float ss = 0.0f;
    #pragma unroll
    for (int u = 0; u < 16; ++u) ss += sred[r * 17 + u] * expf(mred[r * 17 + u] - mm);
    mF[i] = mm; sF[i] = ss;
  }

  const int d0 = tid & 63;
  const int r0 = tid >> 6;
  int pv[16][4] = {};

  for (int s0 = 0; s0 <= t0; s0 += 64) {
    __syncthreads();
    {
      int row = tid >> 2, kc = tid & 3;
      const int8_t* src = K8 + ((size_t)h * T_ + s0 + row) * D_ + kc * 64;
      int4 v0 = ((const int4*)src)[0];
      int4 v1 = ((const int4*)src)[1];
      int4 v2 = ((const int4*)src)[2];
      int4 v3 = ((const int4*)src)[3];
      int* kp = &KV[row * 65 + kc * 16];
      kp[0]  = v0.x; kp[1]  = v0.y; kp[2]  = v0.z; kp[3]  = v0.w;
      kp[4]  = v1.x; kp[5]  = v1.y; kp[6]  = v1.z; kp[7]  = v1.w;
      kp[8]  = v2.x; kp[9]  = v2.y; kp[10] = v2.z; kp[11] = v2.w;
      kp[12] = v3.x; kp[13] = v3.y; kp[14] = v3.z; kp[15] = v3.w;
    }
    __syncthreads();
    int acc[4][4] = {};
    #pragma unroll 8
    for (int kk = 0; kk < 64; ++kk) {
      int a[4], b[4];
      #pragma unroll
      for (int i = 0; i < 4; ++i) a[i] = Qs[(ty * 4 + i) * 65 + kk];
      #pragma unroll
      for (int j = 0; j < 4; ++j) b[j] = KV[(tx * 4 + j) * 65 + kk];
      #pragma unroll
      for (int i = 0; i < 4; ++i)
        #pragma unroll
        for (int j = 0; j < 4; ++j)
          acc[i][j] = dot4(a[i], b[j], acc[i][j]);
    }
    const bool diag = (s0 == t0);
    #pragma unroll
    for (int i = 0; i < 4; ++i) {
      const int trow = t0 + ty * 4 + i;
      int pk = 0;
      #pragma unroll
      for (int j = 0; j < 4; ++j) {
        const int s = s0 + tx * 4 + j;
        int q = 0;
        if (!diag || s <= trow) {
          float l = __fmul_rn(aqk, (float)acc[i][j]);
          float p = expf(l - mF[i]) / sF[i];
          q = (int)rintf(__fmul_rn(p, 127.0f));
        }
        pk |= (q & 255) << (8 * j);
      }
      pi8T[(ty * 4 + i) * 17 + tx] = pk;
    }
    __syncthreads();
    {
      int sc = tid >> 4, dq = tid & 15;
      const int8_t* vsrc = V8 + ((size_t)h * T_ + s0 + 4 * sc) * D_ + dq * 16;
      int4 rv0 = ((const int4*)(vsrc + 0 * D_))[0];
      int4 rv1 = ((const int4*)(vsrc + 1 * D_))[0];
      int4 rv2 = ((const int4*)(vsrc + 2 * D_))[0];
      int4 rv3 = ((const int4*)(vsrc + 3 * D_))[0];
      int rr0[4] = {rv0.x, rv0.y, rv0.z, rv0.w};
      int rr1[4] = {rv1.x, rv1.y, rv1.z, rv1.w};
      int rr2[4] = {rv2.x, rv2.y, rv2.z, rv2.w};
      int rr3[4] = {rv3.x, rv3.y, rv3.z, rv3.w};
      int* vt = &KV[sc * 264 + dq * 16];
      #pragma unroll
      for (int u = 0; u < 4; ++u) {
        #pragma unroll
        for (int b = 0; b < 4; ++b) {
          int sh = 8 * b;
          vt[u * 4 + b] = ((rr0[u] >> sh) & 255) |
                          (((rr1[u] >> sh) & 255) << 8) |
                          (((rr2[u] >> sh) & 255) << 16) |
                          (((rr3[u] >> sh) & 255) << 24);
        }
      }
    }
    __syncthreads();
    #pragma unroll
    for (int sc = 0; sc < 16; ++sc) {
      int4 vv = *(const int4*)&KV[sc * 264 + d0 * 4];
      #pragma unroll
      for (int k = 0; k < 16; ++k) {
        int p = pi8T[(r0 + 4 * k) * 17 + sc];
        pv[k][0] = dot4(p, vv.x, pv[k][0]);
        pv[k][1] = dot4(p, vv.y, pv[k][1]);
        pv[k][2] = dot4(p, vv.z, pv[k][2]);
        pv[k][3] = dot4(p, vv.w, pv[k][3]);
      }
    }
  }

  #pragma unroll
  for (int k = 0; k < 16; ++k) {
    const int t = t0 + r0 + 4 * k;
    int q[4];
    #pragma unroll
    for (int b = 0; b < 4; ++b) {
      float y = rintf(__fmul_rn(apv, (float)pv[k][b]));
      y = fminf(fmaxf(y, -128.0f), 127.0f);
      q[b] = (int)y;
    }
    int packed = (q[0] & 255) | ((q[1] & 255) << 8) | ((q[2] & 255) << 16) | ((q[3] & 255) << 24);
    *(int*)(attn8 + (size_t)t * E_ + h * D_ + d0 * 4) = packed;
  }
}

// =============== fallback dot4 kernels (small-ws path, unchanged) ===========
__global__ __launch_bounds__(256) void qkv_gemm_fb(
    const int* __restrict__ xp,
    const int* __restrict__ Wqp, const int* __restrict__ bq,
    const int* __restrict__ Wkp, const int* __restrict__ bk,
    const int* __restrict__ Wvp, const int* __restrict__ bv,
    const float* __restrict__ alpq, const float* __restrict__ betq,
    const float* __restrict__ alpk, const float* __restrict__ betk,
    const float* __restrict__ alpv, const float* __restrict__ betv,
    const float* __restrict__ sinT, const float* __restrict__ cosT,
    int8_t* __restrict__ Q8, int8_t* __restrict__ K8, int8_t* __restrict__ V8)
{
  const int mode = blockIdx.z;
  const int* __restrict__ Wp = (mode == 0) ? Wqp : (mode == 1 ? Wkp : Wvp);
  const int* __restrict__ bs = (mode == 0) ? bq  : (mode == 1 ? bk  : bv);
  const float alpha = (mode == 0) ? alpq[0] : (mode == 1 ? alpk[0] : alpv[0]);
  const float beta  = (mode == 0) ? betq[0] : (mode == 1 ? betk[0] : betv[0]);

  __shared__ int As[64 * 17];
  __shared__ int Bs[64 * 17];
  const int tid = threadIdx.x;
  const int tx = tid & 15, ty = tid >> 4;
  const int t0 = blockIdx.x * 64, o0 = blockIdx.y * 64;
  const int lrow = tid >> 2, lc = tid & 3;
  int acc[4][4] = {};

  for (int e0 = 0; e0 < E_; e0 += 64) {
    const int* xr = xp + (size_t)(t0 + lrow) * E_ + e0 + lc * 16;
    const int* wr = Wp + (size_t)(o0 + lrow) * E_ + e0 + lc * 16;
    int a4[4], b4[4];
    #pragma unroll
    for (int u = 0; u < 4; ++u) a4[u] = pack4i(((const int4*)xr)[u]);
    #pragma unroll
    for (int u = 0; u < 4; ++u) b4[u] = pack4i(((const int4*)wr)[u]);
    __syncthreads();
    int* ap = &As[lrow * 17 + lc * 4];
    ap[0] = a4[0]; ap[1] = a4[1]; ap[2] = a4[2]; ap[3] = a4[3];
    int* bp = &Bs[lrow * 17 + lc * 4];
    bp[0] = b4[0]; bp[1] = b4[1]; bp[2] = b4[2]; bp[3] = b4[3];
    __syncthreads();
    #pragma unroll
    for (int kk = 0; kk < 16; ++kk) {
      int a[4], b[4];
      #pragma unroll
      for (int i = 0; i < 4; ++i) a[i] = As[(ty * 4 + i) * 17 + kk];
      #pragma unroll
      for (int j = 0; j < 4; ++j) b[j] = Bs[(tx * 4 + j) * 17 + kk];
      #pragma unroll
      for (int i = 0; i < 4; ++i)
        #pragma unroll
        for (int j = 0; j < 4; ++j)
          acc[i][j] = dot4(a[i], b[j], acc[i][j]);
    }
  }

  const int ob = o0 + tx * 4;
  const int h  = ob >> 8;
  const int dd = ob & 255;
  int8_t* __restrict__ dst = (mode == 0) ? Q8 : (mode == 1 ? K8 : V8);
  #pragma unroll
  for (int i = 0; i < 4; ++i) {
    const int t = t0 + ty * 4 + i;
    float y[4];
    #pragma unroll
    for (int j = 0; j < 4; ++j) {
      float v = __fadd_rn(__fmul_rn(alpha, (float)acc[i][j]),
                          __fmul_rn(beta, (float)bs[ob + j]));
      v = rintf(v);
      y[j] = fminf(fmaxf(v, -128.0f), 127.0f);
    }
    int q0, q1, q2, q3;
    if (mode < 2 && dd < 64) {
      const int j0 = dd >> 1;
      const float s0 = sinT[t * NF + j0],     c0 = cosT[t * NF + j0];
      const float s1 = sinT[t * NF + j0 + 1], c1 = cosT[t * NF + j0 + 1];
      float r0 = __fadd_rn(__fmul_rn(y[0], c0), __fmul_rn(-y[1], s0));
      float r1 = __fadd_rn(__fmul_rn(y[1], c0), __fmul_rn( y[0], s0));
      float r2 = __fadd_rn(__fmul_rn(y[2], c1), __fmul_rn(-y[3], s1));
      float r3 = __fadd_rn(__fmul_rn(y[3], c1), __fmul_rn( y[2], s1));
      q0 = (int)fminf(fmaxf(truncf(r0), -128.0f), 127.0f);
      q1 = (int)fminf(fmaxf(truncf(r1), -128.0f), 127.0f);
      q2 = (int)fminf(fmaxf(truncf(r2), -128.0f), 127.0f);
      q3 = (int)fminf(fmaxf(truncf(r3), -128.0f), 127.0f);
    } else {
      q0 = (int)y[0]; q1 = (int)y[1]; q2 = (int)y[2]; q3 = (int)y[3];
    }
    int packed = (q0 & 255) | ((q1 & 255) << 8) | ((q2 & 255) << 16) | ((q3 & 255) << 24);
    *(int*)(dst + ((size_t)h * T_ + t) * D_ + dd) = packed;
  }
}

__global__ __launch_bounds__(256) void out_gemm_fb(
    const int8_t* __restrict__ xa, const int* __restrict__ Wop,
    const float* __restrict__ b_out, const float* __restrict__ p_aout,
    float* __restrict__ out)
{
  __shared__ int As[64 * 17];
  __shared__ int Bs[64 * 17];
  const float alpha = p_aout[0];
  const int tid = threadIdx.x;
  const int tx = tid & 15, ty = tid >> 4;
  const int t0 = blockIdx.x * 64, o0 = blockIdx.y * 64;
  const int lrow = tid >> 2, lc = tid & 3;
  int acc[4][4] = {};

  for (int e0 = 0; e0 < E_; e0 += 64) {
    int4 av4 = *(const int4*)(xa + (size_t)(t0 + lrow) * E_ + e0 + lc * 16);
    const int* wr = Wop + (size_t)(o0 + lrow) * E_ + e0 + lc * 16;
    int b4[4];
    #pragma unroll
    for (int u = 0; u < 4; ++u) b4[u] = pack4i(((const int4*)wr)[u]);
    __syncthreads();
    int* ap = &As[lrow * 17 + lc * 4];
    ap[0] = av4.x; ap[1] = av4.y; ap[2] = av4.z; ap[3] = av4.w;
    int* bp = &Bs[lrow * 17 + lc * 4];
    bp[0] = b4[0]; bp[1] = b4[1]; bp[2] = b4[2]; bp[3] = b4[3];
    __syncthreads();
    #pragma unroll
    for (int kk = 0; kk < 16; ++kk) {
      int a[4], b[4];
      #pragma unroll
      for (int i = 0; i < 4; ++i) a[i] = As[(ty * 4 + i) * 17 + kk];
      #pragma unroll
      for (int j = 0; j < 4; ++j) b[j] = Bs[(tx * 4 + j) * 17 + kk];
      #pragma unroll
      for (int i = 0; i < 4; ++i)
        #pragma unroll
        for (int j = 0; j < 4; ++j)
          acc[i][j] = dot4(a[i], b[j], acc[i][j]);
    }
  }
  #pragma unroll
  for (int i = 0; i < 4; ++i) {
    const int t = t0 + ty * 4 + i;
    const int ob = o0 + tx * 4;
    #pragma unroll
    for (int j = 0; j < 4; ++j) {
      out[(size_t)t * E_ + ob + j] =
          __fadd_rn(__fmul_rn(alpha, (float)acc[i][j]), b_out[ob + j]);
    }
  }
}

extern "C" void kernel_launch(void* const* d_in, const int* in_sizes, int n_in,
                              void* d_out, int out_size, void* d_ws, size_t ws_size,
                              hipStream_t stream) {
  const int* hs   = (const int*)d_in[0];
  const int* Wq   = (const int*)d_in[1];
  const int* bq   = (const int*)d_in[2];
  const int* Wk   = (const int*)d_in[3];
  const int* bk   = (const int*)d_in[4];
  const int* Wv   = (const int*)d_in[5];
  const int* bv   = (const int*)d_in[6];
  const int* Wo   = (const int*)d_in[7];
  const float* b_out = (const float*)d_in[8];
  const float* aq   = (const float*)d_in[9];
  const float* btq  = (const float*)d_in[10];
  const float* ak   = (const float*)d_in[11];
  const float* btk  = (const float*)d_in[12];
  const float* av   = (const float*)d_in[13];
  const float* btv  = (const float*)d_in[14];
  const float* aqk  = (const float*)d_in[15];
  const float* apv  = (const float*)d_in[16];
  const float* aout = (const float*)d_in[17];

  const size_t SEG = (size_t)H_ * T_ * D_;          // 8 MB
  char* ws = (char*)d_ws;
  int8_t* Q8    = (int8_t*)ws;
  int8_t* K8    = Q8 + SEG;
  int8_t* V8    = K8 + SEG;
  int8_t* attn8 = V8 + SEG;                          // aliased with x8
  int8_t* x8    = attn8;
  float*  sinT  = (float*)(ws + 4 * SEG);
  float*  cosT  = sinT + T_ * NF;
  int8_t* Wq8   = (int8_t*)(cosT + T_ * NF);
  int8_t* Wk8   = Wq8 + (size_t)E_ * E_;
  int8_t* Wv8   = Wk8 + (size_t)E_ * E_;
  int8_t* Wo8   = Wv8 + (size_t)E_ * E_;
  const size_t NEED = 4 * SEG + 2 * (size_t)T_ * NF * 4 + 4 * (size_t)E_ * E_;
  const bool big = (ws_size >= NEED);

  sincos_kernel<<<(T_ * NF) / 256, 256, 0, stream>>>(sinT, cosT);

  if (big) {
    repack_kernel<<<(T_ * E_ / 16) / 256, 256, 0, stream>>>(hs, x8);
    repack_kernel<<<(E_ * E_ / 16) / 256, 256, 0, stream>>>(Wq, Wq8);
    repack_kernel<<<(E_ * E_ / 16) / 256, 256, 0, stream>>>(Wk, Wk8);
    repack_kernel<<<(E_ * E_ / 16) / 256, 256, 0, stream>>>(Wv, Wv8);
    repack_kernel<<<(E_ * E_ / 16) / 256, 256, 0, stream>>>(Wo, Wo8);
    qkv_gemm_mfma<<<dim3(T_ / 128, E_ / 128, 3), 256, 0, stream>>>(
        x8, Wq8, bq, Wk8, bk, Wv8, bv, aq, btq, ak, btk, av, btv, Q8, K8, V8);
    rope_kernel<<<(2 * H_ * T_ * 4) / 256, 256, 0, stream>>>(Q8, K8, sinT, cosT);
  } else {
    qkv_gemm_fb<<<dim3(T_ / 64, E_ / 64, 3), 256, 0, stream>>>(
        hs, Wq, bq, Wk, bk, Wv, bv, aq, btq, ak, btk, av, btv,
        sinT, cosT, Q8, K8, V8);
  }

  attn_kernel<<<dim3(T_ / 64, H_), 256, 0, stream>>>(Q8, K8, V8, aqk, apv, attn8);

  if (big) {
    out_gemm_mfma<<<dim3(T_ / 128, E_ / 128), 256, 0, stream>>>(
        attn8, Wo8, b_out, aout, (float*)d_out);
  } else {
    out_gemm_fb<<<dim3(T_ / 64, E_ / 64), 256, 0, stream>>>(
        attn8, Wo, b_out, aout, (float*)d_out);
  }
}

// Round 6
// 687.105 us; speedup vs baseline: 4.4313x; 1.6631x over previous
//
#include <hip/hip_runtime.h>
#include <cstdint>
#include <cmath>

#define T_ 2048
#define E_ 4096
#define H_ 16
#define D_ 256
#define NF 32   // rotary freq count (R/2)

typedef int v4i  __attribute__((ext_vector_type(4)));

__device__ __forceinline__ int dot4(int a, int b, int c) {
#if __has_builtin(__builtin_amdgcn_sdot4)
  return __builtin_amdgcn_sdot4(a, b, c, false);
#else
  c += ((a << 24) >> 24) * ((b << 24) >> 24);
  c += ((a << 16) >> 24) * ((b << 16) >> 24);
  c += ((a <<  8) >> 24) * ((b <<  8) >> 24);
  c += (a >> 24) * (b >> 24);
  return c;
#endif
}

__device__ __forceinline__ int pack4i(int4 v) {
  return (v.x & 255) | ((v.y & 255) << 8) | ((v.z & 255) << 16) | (v.w << 24);
}

#define GLD_LDS16(g, l)                                                        \
  __builtin_amdgcn_global_load_lds(                                            \
      (const __attribute__((address_space(1))) void*)(g),                      \
      (__attribute__((address_space(3))) void*)(l), 16, 0, 0)

// ---------------- sin/cos table (double-precision, cast to f32) -------------
__global__ void sincos_kernel(float* __restrict__ sinT, float* __restrict__ cosT) {
  int idx = blockIdx.x * 256 + threadIdx.x;   // t*32 + j
  int t = idx >> 5, j = idx & 31;
  float invf = (float)exp(-(double)j * (log(10000.0) / 32.0));
  float ang = (float)t * invf;                // f32 product, matches reference
  sinT[idx] = (float)sin((double)ang);
  cosT[idx] = (float)cos((double)ang);
}

// ---------------- int32 -> int8 repack (16 elements/thread) -----------------
__global__ __launch_bounds__(256) void repack_kernel(const int* __restrict__ src,
                                                     int8_t* __restrict__ dst) {
  size_t i = (size_t)blockIdx.x * 256 + threadIdx.x;
  const int4* s = (const int4*)src + i * 4;
  int4 a = s[0], b = s[1], c = s[2], d = s[3];
  int4 o;
  o.x = pack4i(a); o.y = pack4i(b); o.z = pack4i(c); o.w = pack4i(d);
  ((int4*)dst)[i] = o;
}

// =================== MFMA int8 GEMM: QKV projection =========================
// grid (T/128, E/128, 3), block 256. mode 2 (V) writes transposed VT[h][d][t].
__global__ __launch_bounds__(256) void qkv_gemm_mfma(
    const int8_t* __restrict__ x8,
    const int8_t* __restrict__ Wq8, const int* __restrict__ bq,
    const int8_t* __restrict__ Wk8, const int* __restrict__ bk,
    const int8_t* __restrict__ Wv8, const int* __restrict__ bv,
    const float* __restrict__ alpq, const float* __restrict__ betq,
    const float* __restrict__ alpk, const float* __restrict__ betk,
    const float* __restrict__ alpv, const float* __restrict__ betv,
    int8_t* __restrict__ Q8, int8_t* __restrict__ K8, int8_t* __restrict__ VT)
{
  const int mode = blockIdx.z;
  const int8_t* __restrict__ W = (mode == 0) ? Wq8 : (mode == 1 ? Wk8 : Wv8);
  const int* __restrict__ bs   = (mode == 0) ? bq  : (mode == 1 ? bk  : bv);
  const float alpha = (mode == 0) ? alpq[0] : (mode == 1 ? alpk[0] : alpv[0]);
  const float beta  = (mode == 0) ? betq[0] : (mode == 1 ? betk[0] : betv[0]);

  __shared__ int8_t As[128 * 64];
  __shared__ int8_t Bs[128 * 64];

  const int tid  = threadIdx.x;
  const int wave = tid >> 6, lane = tid & 63;
  const int wm = wave >> 1, wn = wave & 1;
  const int t0 = blockIdx.x * 128, o0 = blockIdx.y * 128;

  const int srow = lane >> 2;
  const int scol = (lane & 3) * 16;
  const int col  = lane & 15;
  const int quad = lane >> 4;

  v4i acc[4][4] = {};

  const int8_t* gA0 = x8 + (size_t)(t0 + wave * 32 + srow) * E_ + scol;
  const int8_t* gB0 = W  + (size_t)(o0 + wave * 32 + srow) * E_ + scol;

  for (int e0 = 0; e0 < E_; e0 += 64) {
    __syncthreads();
    GLD_LDS16(gA0 + e0,                 As + wave * 2048);
    GLD_LDS16(gA0 + e0 + 16 * E_,       As + wave * 2048 + 1024);
    GLD_LDS16(gB0 + e0,                 Bs + wave * 2048);
    GLD_LDS16(gB0 + e0 + 16 * E_,       Bs + wave * 2048 + 1024);
    __syncthreads();

    v4i a[4], b[4];
    #pragma unroll
    for (int i = 0; i < 4; ++i)
      a[i] = *(const v4i*)(As + (wm * 64 + i * 16 + col) * 64 + quad * 16);
    #pragma unroll
    for (int j = 0; j < 4; ++j)
      b[j] = *(const v4i*)(Bs + (wn * 64 + j * 16 + col) * 64 + quad * 16);
    #pragma unroll
    for (int i = 0; i < 4; ++i)
      #pragma unroll
      for (int j = 0; j < 4; ++j)
        acc[i][j] = __builtin_amdgcn_mfma_i32_16x16x64_i8(a[i], b[j], acc[i][j], 0, 0, 0);
  }

  int8_t* __restrict__ dst = (mode == 0) ? Q8 : (mode == 1 ? K8 : VT);
  #pragma unroll
  for (int j = 0; j < 4; ++j) {
    const int o  = o0 + wn * 64 + j * 16 + col;
    const int h  = o >> 8;
    const int dd = o & 255;
    const float bb = (float)bs[o];
    #pragma unroll
    for (int i = 0; i < 4; ++i) {
      const int tb = t0 + wm * 64 + i * 16 + quad * 4;
      int qb[4];
      #pragma unroll
      for (int r = 0; r < 4; ++r) {
        float v = __fadd_rn(__fmul_rn(alpha, (float)acc[i][j][r]),
                            __fmul_rn(beta, bb));
        v = rintf(v);
        v = fminf(fmaxf(v, -128.0f), 127.0f);
        qb[r] = (int)v;
      }
      if (mode == 2) {
        // VT[h][dd][t]: 4 consecutive t -> one dword store
        int packed = (qb[0] & 255) | ((qb[1] & 255) << 8) |
                     ((qb[2] & 255) << 16) | ((qb[3] & 255) << 24);
        *(int*)(dst + ((size_t)h * 256 + dd) * T_ + tb) = packed;
      } else {
        #pragma unroll
        for (int r = 0; r < 4; ++r)
          dst[((size_t)h * T_ + tb + r) * D_ + dd] = (int8_t)qb[r];
      }
    }
  }
}

// =================== RoPE pass (in-place on Q8/K8, d<64) ====================
__global__ __launch_bounds__(256) void rope_kernel(
    int8_t* __restrict__ Q8, int8_t* __restrict__ K8,
    const float* __restrict__ sinT, const float* __restrict__ cosT)
{
  int idx = blockIdx.x * 256 + threadIdx.x;
  int c = idx & 3;
  int t = (idx >> 2) & (T_ - 1);
  int h = (idx >> 13) & (H_ - 1);
  int m = idx >> 17;
  int8_t* base = (m == 0 ? Q8 : K8) + ((size_t)h * T_ + t) * D_ + c * 16;
  int4 v = *(int4*)base;
  int u[4] = {v.x, v.y, v.z, v.w};
  const int jb = c * 8;
  #pragma unroll
  for (int ui = 0; ui < 4; ++ui) {
    const int j = jb + ui * 2;
    const float s0 = sinT[t * NF + j],     c0 = cosT[t * NF + j];
    const float s1 = sinT[t * NF + j + 1], c1 = cosT[t * NF + j + 1];
    const int w = u[ui];
    float y0 = (float)((w << 24) >> 24);
    float y1 = (float)((w << 16) >> 24);
    float y2 = (float)((w <<  8) >> 24);
    float y3 = (float)(w >> 24);
    float r0 = __fadd_rn(__fmul_rn(y0, c0), __fmul_rn(-y1, s0));
    float r1 = __fadd_rn(__fmul_rn(y1, c0), __fmul_rn( y0, s0));
    float r2 = __fadd_rn(__fmul_rn(y2, c1), __fmul_rn(-y3, s1));
    float r3 = __fadd_rn(__fmul_rn(y3, c1), __fmul_rn( y2, s1));
    int q0 = (int)fminf(fmaxf(truncf(r0), -128.0f), 127.0f);
    int q1 = (int)fminf(fmaxf(truncf(r1), -128.0f), 127.0f);
    int q2 = (int)fminf(fmaxf(truncf(r2), -128.0f), 127.0f);
    int q3 = (int)fminf(fmaxf(truncf(r3), -128.0f), 127.0f);
    u[ui] = (q0 & 255) | ((q1 & 255) << 8) | ((q2 & 255) << 16) | ((q3 & 255) << 24);
  }
  int4 ov; ov.x = u[0]; ov.y = u[1]; ov.z = u[2]; ov.w = u[3];
  *(int4*)base = ov;
}

// =================== MFMA int8 GEMM: output projection =======================
__global__ __launch_bounds__(256) void out_gemm_mfma(
    const int8_t* __restrict__ xa, const int8_t* __restrict__ Wo8,
    const float* __restrict__ b_out, const float* __restrict__ p_aout,
    float* __restrict__ out)
{
  const float alpha = p_aout[0];
  __shared__ int8_t As[128 * 64];
  __shared__ int8_t Bs[128 * 64];

  const int tid  = threadIdx.x;
  const int wave = tid >> 6, lane = tid & 63;
  const int wm = wave >> 1, wn = wave & 1;
  const int t0 = blockIdx.x * 128, o0 = blockIdx.y * 128;
  const int srow = lane >> 2, scol = (lane & 3) * 16;
  const int col = lane & 15, quad = lane >> 4;

  v4i acc[4][4] = {};
  const int8_t* gA0 = xa  + (size_t)(t0 + wave * 32 + srow) * E_ + scol;
  const int8_t* gB0 = Wo8 + (size_t)(o0 + wave * 32 + srow) * E_ + scol;

  for (int e0 = 0; e0 < E_; e0 += 64) {
    __syncthreads();
    GLD_LDS16(gA0 + e0,            As + wave * 2048);
    GLD_LDS16(gA0 + e0 + 16 * E_,  As + wave * 2048 + 1024);
    GLD_LDS16(gB0 + e0,            Bs + wave * 2048);
    GLD_LDS16(gB0 + e0 + 16 * E_,  Bs + wave * 2048 + 1024);
    __syncthreads();

    v4i a[4], b[4];
    #pragma unroll
    for (int i = 0; i < 4; ++i)
      a[i] = *(const v4i*)(As + (wm * 64 + i * 16 + col) * 64 + quad * 16);
    #pragma unroll
    for (int j = 0; j < 4; ++j)
      b[j] = *(const v4i*)(Bs + (wn * 64 + j * 16 + col) * 64 + quad * 16);
    #pragma unroll
    for (int i = 0; i < 4; ++i)
      #pragma unroll
      for (int j = 0; j < 4; ++j)
        acc[i][j] = __builtin_amdgcn_mfma_i32_16x16x64_i8(a[i], b[j], acc[i][j], 0, 0, 0);
  }

  #pragma unroll
  for (int j = 0; j < 4; ++j) {
    const int o = o0 + wn * 64 + j * 16 + col;
    const float bb = b_out[o];
    #pragma unroll
    for (int i = 0; i < 4; ++i) {
      #pragma unroll
      for (int r = 0; r < 4; ++r) {
        const int t = t0 + wm * 64 + i * 16 + quad * 4 + r;
        out[(size_t)t * E_ + o] = __fadd_rn(__fmul_rn(alpha, (float)acc[i][j][r]), bb);
      }
    }
  }
}

// =================== MFMA attention ========================================
// grid (T/64, H), block 256 (4 waves). Wave (wm,wn): S-quadrant rows wm*32,
// cols wn*32 (scores); PV: rows wm*32, d-cols wn*128.
__global__ __launch_bounds__(256) void attn_mfma(
    const int8_t* __restrict__ Q8, const int8_t* __restrict__ K8,
    const int8_t* __restrict__ VT,
    const float* __restrict__ p_aqk, const float* __restrict__ p_apv,
    int8_t* __restrict__ attn8)
{
  __shared__ int8_t Qs[4 * 4096];     // [slab][64 rows][64B], 16 KB
  __shared__ int8_t KVs[16384];       // K tile [4][64][64] OR Vt [256][64]
  __shared__ int8_t Ps[64][64];       // pi8, A-layout rows=q cols=s
  __shared__ float  mred[64][2];
  __shared__ float  sred[64][2];

  const int h   = blockIdx.y;
  const int t0  = blockIdx.x * 64;
  const int tid = threadIdx.x;
  const int wave = tid >> 6, lane = tid & 63;
  const int wm = wave >> 1, wn = wave & 1;
  const int col = lane & 15, quad = lane >> 4;
  const int srow = lane >> 2, scol = (lane & 3) * 16;
  const float aqk = p_aqk[0] * 0.0625f;   // /16 exact pow2, commutes
  const float apv = p_apv[0];

  // stage Q once (4 slabs per wave)
  {
    const int8_t* g = Q8 + ((size_t)h * T_ + t0 + wave * 16 + srow) * D_ + scol;
    #pragma unroll
    for (int c = 0; c < 4; ++c)
      GLD_LDS16(g + c * 64, Qs + c * 4096 + wave * 1024);
  }

  const int nt = t0 / 64 + 1;

  // ---- pass 1: online m/sum, 8 tracked q-rows/lane (C-layout) ----
  float m[8], sm[8];
  #pragma unroll
  for (int u = 0; u < 8; ++u) { m[u] = -INFINITY; sm[u] = 0.0f; }

  for (int it = 0; it < nt; ++it) {
    const int s0 = it * 64;
    __syncthreads();
    {
      const int8_t* g = K8 + ((size_t)h * T_ + s0 + wave * 16 + srow) * D_ + scol;
      #pragma unroll
      for (int c = 0; c < 4; ++c)
        GLD_LDS16(g + c * 64, KVs + c * 4096 + wave * 1024);
    }
    __syncthreads();
    v4i accS[2][2] = {};
    #pragma unroll
    for (int c = 0; c < 4; ++c) {
      v4i a[2], b[2];
      #pragma unroll
      for (int i = 0; i < 2; ++i)
        a[i] = *(const v4i*)(Qs + c * 4096 + (wm * 32 + i * 16 + col) * 64 + quad * 16);
      #pragma unroll
      for (int j = 0; j < 2; ++j)
        b[j] = *(const v4i*)(KVs + c * 4096 + (wn * 32 + j * 16 + col) * 64 + quad * 16);
      #pragma unroll
      for (int i = 0; i < 2; ++i)
        #pragma unroll
        for (int j = 0; j < 2; ++j)
          accS[i][j] = __builtin_amdgcn_mfma_i32_16x16x64_i8(a[i], b[j], accS[i][j], 0, 0, 0);
    }
    const bool diag = (s0 == t0);
    #pragma unroll
    for (int i = 0; i < 2; ++i) {
      #pragma unroll
      for (int r = 0; r < 4; ++r) {
        const int ri = i * 4 + r;
        const int qrow = t0 + wm * 32 + i * 16 + quad * 4 + r;
        #pragma unroll
        for (int j = 0; j < 2; ++j) {
          const int s = s0 + wn * 32 + j * 16 + col;
          if (!diag || s <= qrow) {
            float l = __fmul_rn(aqk, (float)accS[i][j][r]);
            if (l > m[ri]) { sm[ri] = sm[ri] * expf(m[ri] - l) + 1.0f; m[ri] = l; }
            else           { sm[ri] += expf(l - m[ri]); }
          }
        }
      }
    }
  }

  // reduce over the 16 col-lanes (NaN-guarded for fully-masked halves)
  #pragma unroll
  for (int u = 0; u < 8; ++u) {
    #pragma unroll
    for (int off = 1; off < 16; off <<= 1) {
      float om = __shfl_xor(m[u], off);
      float os = __shfl_xor(sm[u], off);
      float mm = fmaxf(m[u], om);
      float e1 = (m[u] == mm) ? 1.0f : expf(m[u] - mm);
      float e2 = (om   == mm) ? 1.0f : expf(om - mm);
      sm[u] = sm[u] * e1 + os * e2;
      m[u] = mm;
    }
  }
  // cross-wave (wn) reduce via LDS
  __syncthreads();
  if (col == 0) {
    #pragma unroll
    for (int u = 0; u < 8; ++u) {
      int row = wm * 32 + (u >> 2) * 16 + quad * 4 + (u & 3);
      mred[row][wn] = m[u];
      sred[row][wn] = sm[u];
    }
  }
  __syncthreads();
  float mF[8], sF[8];
  #pragma unroll
  for (int u = 0; u < 8; ++u) {
    int row = wm * 32 + (u >> 2) * 16 + quad * 4 + (u & 3);
    float m0 = mred[row][0], m1 = mred[row][1];
    float sa = sred[row][0], sb = sred[row][1];
    float mm = fmaxf(m0, m1);
    float e0 = (m0 == mm) ? 1.0f : expf(m0 - mm);
    float e1 = (m1 == mm) ? 1.0f : expf(m1 - mm);
    mF[u] = mm;
    sF[u] = __fadd_rn(__fmul_rn(sa, e0), __fmul_rn(sb, e1));
  }

  // ---- pass 2: recompute scores, quantize -> Ps, PV via MFMA ----
  v4i pv[2][8] = {};
  for (int it = 0; it < nt; ++it) {
    const int s0 = it * 64;
    __syncthreads();                 // prev iter's KVs/Ps reads done
    {
      const int8_t* g = K8 + ((size_t)h * T_ + s0 + wave * 16 + srow) * D_ + scol;
      #pragma unroll
      for (int c = 0; c < 4; ++c)
        GLD_LDS16(g + c * 64, KVs + c * 4096 + wave * 1024);
    }
    __syncthreads();                 // K tile ready
    v4i accS[2][2] = {};
    #pragma unroll
    for (int c = 0; c < 4; ++c) {
      v4i a[2], b[2];
      #pragma unroll
      for (int i = 0; i < 2; ++i)
        a[i] = *(const v4i*)(Qs + c * 4096 + (wm * 32 + i * 16 + col) * 64 + quad * 16);
      #pragma unroll
      for (int j = 0; j < 2; ++j)
        b[j] = *(const v4i*)(KVs + c * 4096 + (wn * 32 + j * 16 + col) * 64 + quad * 16);
      #pragma unroll
      for (int i = 0; i < 2; ++i)
        #pragma unroll
        for (int j = 0; j < 2; ++j)
          accS[i][j] = __builtin_amdgcn_mfma_i32_16x16x64_i8(a[i], b[j], accS[i][j], 0, 0, 0);
    }
    __syncthreads();                 // all waves done reading K tile
    {
      // stage V^T tile: Vt[256 d][64 s] bytes
      #pragma unroll
      for (int c = 0; c < 4; ++c) {
        const int drow = (wave * 4 + c) * 16 + srow;
        GLD_LDS16(VT + ((size_t)h * 256 + drow) * T_ + s0 + scol,
                  KVs + (wave * 4 + c) * 1024);
      }
    }
    const bool diag = (s0 == t0);
    #pragma unroll
    for (int i = 0; i < 2; ++i) {
      #pragma unroll
      for (int r = 0; r < 4; ++r) {
        const int ri = i * 4 + r;
        const int qrow = t0 + wm * 32 + i * 16 + quad * 4 + r;
        #pragma unroll
        for (int j = 0; j < 2; ++j) {
          const int s = s0 + wn * 32 + j * 16 + col;
          int q = 0;
          if (!diag || s <= qrow) {
            float l = __fmul_rn(aqk, (float)accS[i][j][r]);
            float p = expf(l - mF[ri]) / sF[ri];       // division first (ref order)
            q = (int)rintf(__fmul_rn(p, 127.0f));
          }
          Ps[wm * 32 + i * 16 + quad * 4 + r][wn * 32 + j * 16 + col] = (int8_t)q;
        }
      }
    }
    __syncthreads();                 // Vt + Ps ready
    v4i a2[2], b2[8];
    #pragma unroll
    for (int i = 0; i < 2; ++i)
      a2[i] = *(const v4i*)&Ps[wm * 32 + i * 16 + col][quad * 16];
    #pragma unroll
    for (int dt = 0; dt < 8; ++dt)
      b2[dt] = *(const v4i*)(KVs + (wn * 128 + dt * 16 + col) * 64 + quad * 16);
    #pragma unroll
    for (int i = 0; i < 2; ++i)
      #pragma unroll
      for (int dt = 0; dt < 8; ++dt)
        pv[i][dt] = __builtin_amdgcn_mfma_i32_16x16x64_i8(a2[i], b2[dt], pv[i][dt], 0, 0, 0);
  }

  // ---- epilogue: quantize PV (C-layout), byte stores ----
  #pragma unroll
  for (int i = 0; i < 2; ++i) {
    #pragma unroll
    for (int r = 0; r < 4; ++r) {
      const int t = t0 + wm * 32 + i * 16 + quad * 4 + r;
      #pragma unroll
      for (int dt = 0; dt < 8; ++dt) {
        const int d = wn * 128 + dt * 16 + col;
        float y = rintf(__fmul_rn(apv, (float)pv[i][dt][r]));
        y = fminf(fmaxf(y, -128.0f), 127.0f);
        attn8[(size_t)t * E_ + h * D_ + d] = (int8_t)(int)y;
      }
    }
  }
}

// =============== fallback dot4 kernels (small-ws path) ======================
__global__ __launch_bounds__(256) void qkv_gemm_fb(
    const int* __restrict__ xp,
    const int* __restrict__ Wqp, const int* __restrict__ bq,
    const int* __restrict__ Wkp, const int* __restrict__ bk,
    const int* __restrict__ Wvp, const int* __restrict__ bv,
    const float* __restrict__ alpq, const float* __restrict__ betq,
    const float* __restrict__ alpk, const float* __restrict__ betk,
    const float* __restrict__ alpv, const float* __restrict__ betv,
    const float* __restrict__ sinT, const float* __restrict__ cosT,
    int8_t* __restrict__ Q8, int8_t* __restrict__ K8, int8_t* __restrict__ VT)
{
  const int mode = blockIdx.z;
  const int* __restrict__ Wp = (mode == 0) ? Wqp : (mode == 1 ? Wkp : Wvp);
  const int* __restrict__ bs = (mode == 0) ? bq  : (mode == 1 ? bk  : bv);
  const float alpha = (mode == 0) ? alpq[0] : (mode == 1 ? alpk[0] : alpv[0]);
  const float beta  = (mode == 0) ? betq[0] : (mode == 1 ? betk[0] : betv[0]);

  __shared__ int As[64 * 17];
  __shared__ int Bs[64 * 17];
  const int tid = threadIdx.x;
  const int tx = tid & 15, ty = tid >> 4;
  const int t0 = blockIdx.x * 64, o0 = blockIdx.y * 64;
  const int lrow = tid >> 2, lc = tid & 3;
  int acc[4][4] = {};

  for (int e0 = 0; e0 < E_; e0 += 64) {
    const int* xr = xp + (size_t)(t0 + lrow) * E_ + e0 + lc * 16;
    const int* wr = Wp + (size_t)(o0 + lrow) * E_ + e0 + lc * 16;
    int a4[4], b4[4];
    #pragma unroll
    for (int u = 0; u < 4; ++u) a4[u] = pack4i(((const int4*)xr)[u]);
    #pragma unroll
    for (int u = 0; u < 4; ++u) b4[u] = pack4i(((const int4*)wr)[u]);
    __syncthreads();
    int* ap = &As[lrow * 17 + lc * 4];
    ap[0] = a4[0]; ap[1] = a4[1]; ap[2] = a4[2]; ap[3] = a4[3];
    int* bp = &Bs[lrow * 17 + lc * 4];
    bp[0] = b4[0]; bp[1] = b4[1]; bp[2] = b4[2]; bp[3] = b4[3];
    __syncthreads();
    #pragma unroll
    for (int kk = 0; kk < 16; ++kk) {
      int a[4], b[4];
      #pragma unroll
      for (int i = 0; i < 4; ++i) a[i] = As[(ty * 4 + i) * 17 + kk];
      #pragma unroll
      for (int j = 0; j < 4; ++j) b[j] = Bs[(tx * 4 + j) * 17 + kk];
      #pragma unroll
      for (int i = 0; i < 4; ++i)
        #pragma unroll
        for (int j = 0; j < 4; ++j)
          acc[i][j] = dot4(a[i], b[j], acc[i][j]);
    }
  }

  const int ob = o0 + tx * 4;
  const int h  = ob >> 8;
  const int dd = ob & 255;
  #pragma unroll
  for (int i = 0; i < 4; ++i) {
    const int t = t0 + ty * 4 + i;
    float y[4];
    #pragma unroll
    for (int j = 0; j < 4; ++j) {
      float v = __fadd_rn(__fmul_rn(alpha, (float)acc[i][j]),
                          __fmul_rn(beta, (float)bs[ob + j]));
      v = rintf(v);
      y[j] = fminf(fmaxf(v, -128.0f), 127.0f);
    }
    int q0, q1, q2, q3;
    if (mode < 2 && dd < 64) {
      const int j0 = dd >> 1;
      const float s0 = sinT[t * NF + j0],     c0 = cosT[t * NF + j0];
      const float s1 = sinT[t * NF + j0 + 1], c1 = cosT[t * NF + j0 + 1];
      float r0 = __fadd_rn(__fmul_rn(y[0], c0), __fmul_rn(-y[1], s0));
      float r1 = __fadd_rn(__fmul_rn(y[1], c0), __fmul_rn( y[0], s0));
      float r2 = __fadd_rn(__fmul_rn(y[2], c1), __fmul_rn(-y[3], s1));
      float r3 = __fadd_rn(__fmul_rn(y[3], c1), __fmul_rn( y[2], s1));
      q0 = (int)fminf(fmaxf(truncf(r0), -128.0f), 127.0f);
      q1 = (int)fminf(fmaxf(truncf(r1), -128.0f), 127.0f);
      q2 = (int)fminf(fmaxf(truncf(r2), -128.0f), 127.0f);
      q3 = (int)fminf(fmaxf(truncf(r3), -128.0f), 127.0f);
    } else {
      q0 = (int)y[0]; q1 = (int)y[1]; q2 = (int)y[2]; q3 = (int)y[3];
    }
    if (mode == 2) {
      VT[((size_t)h * 256 + dd + 0) * T_ + t] = (int8_t)q0;
      VT[((size_t)h * 256 + dd + 1) * T_ + t] = (int8_t)q1;
      VT[((size_t)h * 256 + dd + 2) * T_ + t] = (int8_t)q2;
      VT[((size_t)h * 256 + dd + 3) * T_ + t] = (int8_t)q3;
    } else {
      int8_t* dst = (mode == 0) ? Q8 : K8;
      int packed = (q0 & 255) | ((q1 & 255) << 8) | ((q2 & 255) << 16) | ((q3 & 255) << 24);
      *(int*)(dst + ((size_t)h * T_ + t) * D_ + dd) = packed;
    }
  }
}

__global__ __launch_bounds__(256) void out_gemm_fb(
    const int8_t* __restrict__ xa, const int* __restrict__ Wop,
    const float* __restrict__ b_out, const float* __restrict__ p_aout,
    float* __restrict__ out)
{
  __shared__ int As[64 * 17];
  __shared__ int Bs[64 * 17];
  const float alpha = p_aout[0];
  const int tid = threadIdx.x;
  const int tx = tid & 15, ty = tid >> 4;
  const int t0 = blockIdx.x * 64, o0 = blockIdx.y * 64;
  const int lrow = tid >> 2, lc = tid & 3;
  int acc[4][4] = {};

  for (int e0 = 0; e0 < E_; e0 += 64) {
    int4 av4 = *(const int4*)(xa + (size_t)(t0 + lrow) * E_ + e0 + lc * 16);
    const int* wr = Wop + (size_t)(o0 + lrow) * E_ + e0 + lc * 16;
    int b4[4];
    #pragma unroll
    for (int u = 0; u < 4; ++u) b4[u] = pack4i(((const int4*)wr)[u]);
    __syncthreads();
    int* ap = &As[lrow * 17 + lc * 4];
    ap[0] = av4.x; ap[1] = av4.y; ap[2] = av4.z; ap[3] = av4.w;
    int* bp = &Bs[lrow * 17 + lc * 4];
    bp[0] = b4[0]; bp[1] = b4[1]; bp[2] = b4[2]; bp[3] = b4[3];
    __syncthreads();
    #pragma unroll
    for (int kk = 0; kk < 16; ++kk) {
      int a[4], b[4];
      #pragma unroll
      for (int i = 0; i < 4; ++i) a[i] = As[(ty * 4 + i) * 17 + kk];
      #pragma unroll
      for (int j = 0; j < 4; ++j) b[j] = Bs[(tx * 4 + j) * 17 + kk];
      #pragma unroll
      for (int i = 0; i < 4; ++i)
        #pragma unroll
        for (int j = 0; j < 4; ++j)
          acc[i][j] = dot4(a[i], b[j], acc[i][j]);
    }
  }
  #pragma unroll
  for (int i = 0; i < 4; ++i) {
    const int t = t0 + ty * 4 + i;
    const int ob = o0 + tx * 4;
    #pragma unroll
    for (int j = 0; j < 4; ++j) {
      out[(size_t)t * E_ + ob + j] =
          __fadd_rn(__fmul_rn(alpha, (float)acc[i][j]), b_out[ob + j]);
    }
  }
}

extern "C" void kernel_launch(void* const* d_in, const int* in_sizes, int n_in,
                              void* d_out, int out_size, void* d_ws, size_t ws_size,
                              hipStream_t stream) {
  const int* hs   = (const int*)d_in[0];
  const int* Wq   = (const int*)d_in[1];
  const int* bq   = (const int*)d_in[2];
  const int* Wk   = (const int*)d_in[3];
  const int* bk   = (const int*)d_in[4];
  const int* Wv   = (const int*)d_in[5];
  const int* bv   = (const int*)d_in[6];
  const int* Wo   = (const int*)d_in[7];
  const float* b_out = (const float*)d_in[8];
  const float* aq   = (const float*)d_in[9];
  const float* btq  = (const float*)d_in[10];
  const float* ak   = (const float*)d_in[11];
  const float* btk  = (const float*)d_in[12];
  const float* av   = (const float*)d_in[13];
  const float* btv  = (const float*)d_in[14];
  const float* aqk  = (const float*)d_in[15];
  const float* apv  = (const float*)d_in[16];
  const float* aout = (const float*)d_in[17];

  const size_t SEG = (size_t)H_ * T_ * D_;          // 8 MB
  char* ws = (char*)d_ws;
  int8_t* Q8    = (int8_t*)ws;
  int8_t* K8    = Q8 + SEG;
  int8_t* VT    = K8 + SEG;                          // transposed V [h][d][t]
  int8_t* attn8 = VT + SEG;                          // aliased with x8
  int8_t* x8    = attn8;
  float*  sinT  = (float*)(ws + 4 * SEG);
  float*  cosT  = sinT + T_ * NF;
  int8_t* Wq8   = (int8_t*)(cosT + T_ * NF);
  int8_t* Wk8   = Wq8 + (size_t)E_ * E_;
  int8_t* Wv8   = Wk8 + (size_t)E_ * E_;
  int8_t* Wo8   = Wv8 + (size_t)E_ * E_;
  const size_t NEED = 4 * SEG + 2 * (size_t)T_ * NF * 4 + 4 * (size_t)E_ * E_;
  const bool big = (ws_size >= NEED);

  sincos_kernel<<<(T_ * NF) / 256, 256, 0, stream>>>(sinT, cosT);

  if (big) {
    repack_kernel<<<(T_ * E_ / 16) / 256, 256, 0, stream>>>(hs, x8);
    repack_kernel<<<(E_ * E_ / 16) / 256, 256, 0, stream>>>(Wq, Wq8);
    repack_kernel<<<(E_ * E_ / 16) / 256, 256, 0, stream>>>(Wk, Wk8);
    repack_kernel<<<(E_ * E_ / 16) / 256, 256, 0, stream>>>(Wv, Wv8);
    repack_kernel<<<(E_ * E_ / 16) / 256, 256, 0, stream>>>(Wo, Wo8);
    qkv_gemm_mfma<<<dim3(T_ / 128, E_ / 128, 3), 256, 0, stream>>>(
        x8, Wq8, bq, Wk8, bk, Wv8, bv, aq, btq, ak, btk, av, btv, Q8, K8, VT);
    rope_kernel<<<(2 * H_ * T_ * 4) / 256, 256, 0, stream>>>(Q8, K8, sinT, cosT);
  } else {
    qkv_gemm_fb<<<dim3(T_ / 64, E_ / 64, 3), 256, 0, stream>>>(
        hs, Wq, bq, Wk, bk, Wv, bv, aq, btq, ak, btk, av, btv,
        sinT, cosT, Q8, K8, VT);
  }

  attn_mfma<<<dim3(T_ / 64, H_), 256, 0, stream>>>(Q8, K8, VT, aqk, apv, attn8);

  if (big) {
    out_gemm_mfma<<<dim3(T_ / 128, E_ / 128), 256, 0, stream>>>(
        attn8, Wo8, b_out, aout, (float*)d_out);
  } else {
    out_gemm_fb<<<dim3(T_ / 64, E_ / 64), 256, 0, stream>>>(
        attn8, Wo, b_out, aout, (float*)d_out);
  }
}